// Round 2
// baseline (384.614 us; speedup 1.0000x reference)
//
#include <hip/hip_runtime.h>
#include <hip/hip_bf16.h>

typedef __bf16 bf16_t;
typedef __bf16 bf16x8 __attribute__((ext_vector_type(8)));
typedef float floatx4 __attribute__((ext_vector_type(4)));

#define EMBED 512
#define S_LEN 1024
#define NH 8
#define HD 64

static __device__ __forceinline__ float bf2f(bf16_t v) {
    unsigned short u = __builtin_bit_cast(unsigned short, v);
    unsigned int x = ((unsigned int)u) << 16;
    return __builtin_bit_cast(float, x);
}
static __device__ __forceinline__ bf16_t f2bf(float f) {
    unsigned int x = __builtin_bit_cast(unsigned int, f);
    unsigned int lsb = (x >> 16) & 1u;
    x += 0x7fffu + lsb;                 // round-to-nearest-even
    unsigned short u = (unsigned short)(x >> 16);
    return __builtin_bit_cast(bf16_t, u);
}

// ---------------------------------------------------------------------------
// Kernel 0: f32 -> bf16 weight conversion (512x512 = 262144 elems)
// ---------------------------------------------------------------------------
__global__ __launch_bounds__(256) void cvt_kernel(const float* __restrict__ src,
                                                  bf16_t* __restrict__ dst) {
    int i = (blockIdx.x * 256 + threadIdx.x) * 8;
#pragma unroll
    for (int j = 0; j < 8; ++j) dst[i + j] = f2bf(src[i + j]);
}

// ---------------------------------------------------------------------------
// Kernel 1: x[b,c,s] (f32 NCHW, s=h*32+w) -> LayerNorm over c -> xn[b,s,c] bf16
// one block (256 thr) per (b,s); each thread handles c=t and c=t+256
// ---------------------------------------------------------------------------
__global__ __launch_bounds__(256) void ln_tr_kernel(const float* __restrict__ x,
                                                    const float* __restrict__ gamma,
                                                    const float* __restrict__ beta,
                                                    bf16_t* __restrict__ xn) {
    int bs = blockIdx.x;
    int b = bs >> 10;
    const float* xp = x + ((size_t)b * EMBED) * S_LEN + (bs & 1023);
    int t = threadIdx.x;
    float v0 = xp[(size_t)t * S_LEN];
    float v1 = xp[(size_t)(t + 256) * S_LEN];
    float sum = v0 + v1;
    float ss  = v0 * v0 + v1 * v1;
#pragma unroll
    for (int off = 32; off >= 1; off >>= 1) {
        sum += __shfl_xor(sum, off);
        ss  += __shfl_xor(ss, off);
    }
    __shared__ float rs[4], rq[4];
    int w = t >> 6;
    if ((t & 63) == 0) { rs[w] = sum; rq[w] = ss; }
    __syncthreads();
    sum = rs[0] + rs[1] + rs[2] + rs[3];
    ss  = rq[0] + rq[1] + rq[2] + rq[3];
    float mu   = sum * (1.0f / EMBED);
    float var  = ss * (1.0f / EMBED) - mu * mu;
    float rstd = rsqrtf(var + 1e-5f);
    bf16_t* op = xn + (size_t)bs * EMBED;
    op[t]       = f2bf((v0 - mu) * rstd * gamma[t]       + beta[t]);
    op[t + 256] = f2bf((v1 - mu) * rstd * gamma[t + 256] + beta[t + 256]);
}

// ---------------------------------------------------------------------------
// Kernel 2: GEMM  Y[m,n] = sum_k X[m,k]*W[n,k] + bias[n]   (X,W,Y bf16; bias f32)
// M=8192, N=K=512.  64x64 tile/block, 4 waves, each wave 16 rows x 64 cols.
// mfma_f32_16x16x32_bf16; A/B frag: idx=lane&15, k=(lane>>4)*8+j;
// C/D: col=lane&15, row=(lane>>4)*4+reg  (HW-verified layouts).
// ---------------------------------------------------------------------------
__global__ __launch_bounds__(256) void gemm_bias_kernel(const bf16_t* __restrict__ X,
                                                        const bf16_t* __restrict__ W,
                                                        const float* __restrict__ bias,
                                                        bf16_t* __restrict__ Y) {
    int lane = threadIdx.x & 63;
    int w    = threadIdx.x >> 6;
    int g    = lane >> 4, n16 = lane & 15;
    int row0 = blockIdx.x * 64 + w * 16;
    int col0 = blockIdx.y * 64;
    const bf16_t* xr = X + (size_t)(row0 + n16) * EMBED + g * 8;
    const bf16_t* wr = W + (size_t)(col0 + n16) * EMBED + g * 8;
    floatx4 acc[4] = {};
    for (int k = 0; k < EMBED; k += 32) {
        bf16x8 a = *(const bf16x8*)(xr + k);
#pragma unroll
        for (int nt = 0; nt < 4; ++nt) {
            bf16x8 bfr = *(const bf16x8*)(wr + (size_t)nt * 16 * EMBED + k);
            acc[nt] = __builtin_amdgcn_mfma_f32_16x16x32_bf16(a, bfr, acc[nt], 0, 0, 0);
        }
    }
#pragma unroll
    for (int nt = 0; nt < 4; ++nt) {
        int col = col0 + nt * 16 + n16;
        float bv = bias[col];
#pragma unroll
        for (int r = 0; r < 4; ++r) {
            int rw = row0 + g * 4 + r;
            Y[(size_t)rw * EMBED + col] = f2bf(acc[nt][r] + bv);
        }
    }
}

// ---------------------------------------------------------------------------
// Kernel 3: flash attention.  block = (qt, h, b), 256 thr = 4 waves,
// each wave owns 16 q-rows; K/V staged 32 keys at a time in LDS (V transposed);
// P goes fp32->bf16 through LDS to re-enter A-operand layout for PV.
// q/k/v layout: [b, s, h*64+d] (c-contiguous), all bf16.
// ---------------------------------------------------------------------------
__global__ __launch_bounds__(256) void attn_kernel(const bf16_t* __restrict__ q,
                                                   const bf16_t* __restrict__ kk,
                                                   const bf16_t* __restrict__ vv,
                                                   bf16_t* __restrict__ o) {
    __shared__ __align__(16) bf16_t Kl[32 * 64];     // [key][d]
    __shared__ __align__(16) bf16_t Vt[64 * 32];     // [d][key]
    __shared__ __align__(16) bf16_t Pl[4][16 * 32];  // per-wave [qrow][key]
    int qt = blockIdx.x, h = blockIdx.y, b = blockIdx.z;
    int t = threadIdx.x, w = t >> 6, lane = t & 63, g = lane >> 4, n16 = lane & 15;
    size_t base = ((size_t)b * S_LEN) * EMBED + h * HD;
    int qr = qt * 64 + w * 16 + n16;
    const bf16_t* qp = q + base + (size_t)qr * EMBED;
    bf16x8 qf0 = *(const bf16x8*)(qp + g * 8);
    bf16x8 qf1 = *(const bf16x8*)(qp + 32 + g * 8);
    float m_i[4] = {-1e30f, -1e30f, -1e30f, -1e30f};
    float l_i[4] = {0.f, 0.f, 0.f, 0.f};
    floatx4 oacc[4] = {};
    int srow = t >> 3, scol = (t & 7) * 8;
    const float scale = 0.125f;   // 1/sqrt(64)

    for (int kt = 0; kt < S_LEN; kt += 32) {
        // ---- stage K (natural) and V (transposed) tiles ----
        bf16x8 kvec = *(const bf16x8*)(kk + base + (size_t)(kt + srow) * EMBED + scol);
        *(bf16x8*)(&Kl[srow * 64 + scol]) = kvec;
        bf16x8 vvec = *(const bf16x8*)(vv + base + (size_t)(kt + srow) * EMBED + scol);
#pragma unroll
        for (int j = 0; j < 8; ++j) Vt[(scol + j) * 32 + srow] = vvec[j];
        __syncthreads();

        // ---- S = Q K^T for 16 q-rows x 32 keys ----
        floatx4 s0 = {}, s1 = {};
        {
            bf16x8 k0 = *(const bf16x8*)(&Kl[n16 * 64 + g * 8]);
            bf16x8 k1 = *(const bf16x8*)(&Kl[(16 + n16) * 64 + g * 8]);
            s0 = __builtin_amdgcn_mfma_f32_16x16x32_bf16(qf0, k0, s0, 0, 0, 0);
            s1 = __builtin_amdgcn_mfma_f32_16x16x32_bf16(qf0, k1, s1, 0, 0, 0);
            k0 = *(const bf16x8*)(&Kl[n16 * 64 + 32 + g * 8]);
            k1 = *(const bf16x8*)(&Kl[(16 + n16) * 64 + 32 + g * 8]);
            s0 = __builtin_amdgcn_mfma_f32_16x16x32_bf16(qf1, k0, s0, 0, 0, 0);
            s1 = __builtin_amdgcn_mfma_f32_16x16x32_bf16(qf1, k1, s1, 0, 0, 0);
        }

        // ---- online softmax (row = g*4+r, reduce across the 16-lane group) ----
        float p0[4], p1[4], alpha4[4];
#pragma unroll
        for (int r = 0; r < 4; ++r) {
            float a0 = s0[r] * scale, a1 = s1[r] * scale;
            float mx = fmaxf(a0, a1);
#pragma unroll
            for (int off = 1; off <= 8; off <<= 1) mx = fmaxf(mx, __shfl_xor(mx, off));
            float mn = fmaxf(m_i[r], mx);
            float e0 = __expf(a0 - mn), e1 = __expf(a1 - mn);
            float rs2 = e0 + e1;
#pragma unroll
            for (int off = 1; off <= 8; off <<= 1) rs2 += __shfl_xor(rs2, off);
            float al = __expf(m_i[r] - mn);
            l_i[r] = l_i[r] * al + rs2;
            m_i[r] = mn;
            alpha4[r] = al; p0[r] = e0; p1[r] = e1;
        }
#pragma unroll
        for (int nt = 0; nt < 4; ++nt)
#pragma unroll
            for (int r = 0; r < 4; ++r) oacc[nt][r] *= alpha4[r];

        // ---- P: C/D layout -> LDS -> A layout (bf16) ----
#pragma unroll
        for (int r = 0; r < 4; ++r) {
            Pl[w][(g * 4 + r) * 32 + n16]      = f2bf(p0[r]);
            Pl[w][(g * 4 + r) * 32 + 16 + n16] = f2bf(p1[r]);
        }
        __syncthreads();
        bf16x8 pf = *(const bf16x8*)(&Pl[w][n16 * 32 + g * 8]);
#pragma unroll
        for (int nt = 0; nt < 4; ++nt) {
            bf16x8 vf = *(const bf16x8*)(&Vt[(nt * 16 + n16) * 32 + g * 8]);
            oacc[nt] = __builtin_amdgcn_mfma_f32_16x16x32_bf16(pf, vf, oacc[nt], 0, 0, 0);
        }
        __syncthreads();
    }

    // ---- epilogue: O / l_i -> o[b, qrow, h*64+d] ----
#pragma unroll
    for (int nt = 0; nt < 4; ++nt) {
#pragma unroll
        for (int r = 0; r < 4; ++r) {
            int row = qt * 64 + w * 16 + g * 4 + r;
            o[base + (size_t)row * EMBED + nt * 16 + n16] = f2bf(oacc[nt][r] / l_i[r]);
        }
    }
}

// ---------------------------------------------------------------------------
// Kernel 4: out[b,c,s] = tmp[b,s,c](bf16) + x[b,c,s](f32)  -> f32
// (32x32 LDS transpose tile)
// ---------------------------------------------------------------------------
__global__ __launch_bounds__(256) void trres_kernel(const bf16_t* __restrict__ tmp,
                                                    const float* __restrict__ x,
                                                    float* __restrict__ out) {
    __shared__ float T[32][33];
    int tx = threadIdx.x & 31, ty = threadIdx.x >> 5;
    int b = blockIdx.z, c0 = blockIdx.y * 32, s0 = blockIdx.x * 32;
#pragma unroll
    for (int i = 0; i < 4; ++i) {
        int sr = ty + i * 8;
        T[sr][tx] = bf2f(tmp[((size_t)b * S_LEN + s0 + sr) * EMBED + c0 + tx]);
    }
    __syncthreads();
#pragma unroll
    for (int i = 0; i < 4; ++i) {
        int cr = ty + i * 8;
        size_t oi = ((size_t)b * EMBED + c0 + cr) * S_LEN + s0 + tx;
        out[oi] = T[tx][cr] + x[oi];
    }
}

extern "C" void kernel_launch(void* const* d_in, const int* in_sizes, int n_in,
                              void* d_out, int out_size, void* d_ws, size_t ws_size,
                              hipStream_t stream) {
    const float* x     = (const float*)d_in[0];
    const float* Wq    = (const float*)d_in[1];
    const float* bq    = (const float*)d_in[2];
    const float* Wk    = (const float*)d_in[3];
    const float* bk    = (const float*)d_in[4];
    const float* Wv    = (const float*)d_in[5];
    const float* bv    = (const float*)d_in[6];
    const float* Wo    = (const float*)d_in[7];
    const float* bo    = (const float*)d_in[8];
    const float* gamma = (const float*)d_in[9];
    const float* beta  = (const float*)d_in[10];
    float* out = (float*)d_out;

    char* ws = (char*)d_ws;
    const size_t BUF = (size_t)8 * S_LEN * EMBED * sizeof(bf16_t);  // 8 MB
    const size_t WSZ = (size_t)EMBED * EMBED * sizeof(bf16_t);      // 512 KB
    bf16_t* xn  = (bf16_t*)(ws);                  // reused as attn output
    bf16_t* qb  = (bf16_t*)(ws + BUF);            // reused as O-proj tmp
    bf16_t* kb  = (bf16_t*)(ws + 2 * BUF);
    bf16_t* Wqb = (bf16_t*)(ws + 3 * BUF);
    bf16_t* Wkb = (bf16_t*)(ws + 3 * BUF + WSZ);
    bf16_t* Wvb = (bf16_t*)(ws + 3 * BUF + 2 * WSZ);
    bf16_t* Wob = (bf16_t*)(ws + 3 * BUF + 3 * WSZ);
    bf16_t* vb  = (bf16_t*)d_out;                 // lower 8MB of d_out (16MB f32);
                                                  // dead before trres overwrites out
    bf16_t* ab  = xn;
    bf16_t* tb  = qb;

    cvt_kernel<<<dim3(128), 256, 0, stream>>>(Wq, Wqb);
    cvt_kernel<<<dim3(128), 256, 0, stream>>>(Wk, Wkb);
    cvt_kernel<<<dim3(128), 256, 0, stream>>>(Wv, Wvb);
    cvt_kernel<<<dim3(128), 256, 0, stream>>>(Wo, Wob);
    ln_tr_kernel<<<dim3(8 * S_LEN), 256, 0, stream>>>(x, gamma, beta, xn);
    gemm_bias_kernel<<<dim3(128, 8), 256, 0, stream>>>(xn, Wqb, bq, qb);
    gemm_bias_kernel<<<dim3(128, 8), 256, 0, stream>>>(xn, Wkb, bk, kb);
    gemm_bias_kernel<<<dim3(128, 8), 256, 0, stream>>>(xn, Wvb, bv, vb);
    attn_kernel<<<dim3(16, NH, 8), 256, 0, stream>>>(qb, kb, vb, ab);
    gemm_bias_kernel<<<dim3(128, 8), 256, 0, stream>>>(ab, Wob, bo, tb);
    trres_kernel<<<dim3(32, 16, 8), 256, 0, stream>>>(tb, x, out);
}

// Round 3
// 286.910 us; speedup vs baseline: 1.3405x; 1.3405x over previous
//
#include <hip/hip_runtime.h>
#include <hip/hip_bf16.h>

typedef __bf16 bf16_t;
typedef __bf16 bf16x8 __attribute__((ext_vector_type(8)));
typedef float floatx4 __attribute__((ext_vector_type(4)));

#define EMBED 512
#define S_LEN 1024
#define NH 8
#define HD 64
#define LDQ 1536   // row stride of packed qkv output

#define MFMA16(a, b, c) __builtin_amdgcn_mfma_f32_16x16x32_bf16(a, b, c, 0, 0, 0)

static __device__ __forceinline__ float bf2f(bf16_t v) {
    unsigned short u = __builtin_bit_cast(unsigned short, v);
    unsigned int x = ((unsigned int)u) << 16;
    return __builtin_bit_cast(float, x);
}
static __device__ __forceinline__ bf16_t f2bf(float f) {
    unsigned int x = __builtin_bit_cast(unsigned int, f);
    unsigned int lsb = (x >> 16) & 1u;
    x += 0x7fffu + lsb;                 // RNE
    unsigned short u = (unsigned short)(x >> 16);
    return __builtin_bit_cast(bf16_t, u);
}
// truncate-pack 8 f32 -> bf16x8 (for P fragments; P in [0,1], trunc ok)
static __device__ __forceinline__ bf16x8 pack8(floatx4 a, floatx4 b) {
    union { bf16x8 v; unsigned int u[4]; } r;
    r.u[0] = (__builtin_bit_cast(unsigned int, a[0]) >> 16) |
             (__builtin_bit_cast(unsigned int, a[1]) & 0xFFFF0000u);
    r.u[1] = (__builtin_bit_cast(unsigned int, a[2]) >> 16) |
             (__builtin_bit_cast(unsigned int, a[3]) & 0xFFFF0000u);
    r.u[2] = (__builtin_bit_cast(unsigned int, b[0]) >> 16) |
             (__builtin_bit_cast(unsigned int, b[1]) & 0xFFFF0000u);
    r.u[3] = (__builtin_bit_cast(unsigned int, b[2]) >> 16) |
             (__builtin_bit_cast(unsigned int, b[3]) & 0xFFFF0000u);
    return r.v;
}

// ---------------------------------------------------------------------------
// f32 -> bf16 weight conversion (262144 elems per matrix)
// ---------------------------------------------------------------------------
__global__ __launch_bounds__(256) void cvt_kernel(const float* __restrict__ src,
                                                  bf16_t* __restrict__ dst) {
    int i = (blockIdx.x * 256 + threadIdx.x) * 8;
#pragma unroll
    for (int j = 0; j < 8; ++j) dst[i + j] = f2bf(src[i + j]);
}

__global__ __launch_bounds__(512) void pack_bias_kernel(const float* __restrict__ bq,
                                                        const float* __restrict__ bk,
                                                        const float* __restrict__ bv,
                                                        float* __restrict__ out) {
    int i = threadIdx.x;
    out[i] = bq[i]; out[512 + i] = bk[i]; out[1024 + i] = bv[i];
}

// ---------------------------------------------------------------------------
// LN stats: per (b,s) mean/rstd over c.  Coalesced reads along s.
// block = (b, 32-s tile); thread (tc=t>>5, ts=t&31) covers c = tc*64..+63
// ---------------------------------------------------------------------------
__global__ __launch_bounds__(256) void ln_stats_kernel(const float* __restrict__ x,
                                                       float* __restrict__ muA,
                                                       float* __restrict__ rsA) {
    int bid = blockIdx.x;
    int b = bid >> 5, s0 = (bid & 31) * 32;
    int t = threadIdx.x, tc = t >> 5, ts = t & 31;
    const float* xp = x + (size_t)b * EMBED * S_LEN + s0 + ts;
    float sm = 0.f, sq = 0.f;
    for (int i = 0; i < 64; ++i) {
        float v = xp[(size_t)(tc * 64 + i) * S_LEN];
        sm += v; sq += v * v;
    }
    __shared__ float Sm[8][32], Sq[8][32];
    Sm[tc][ts] = sm; Sq[tc][ts] = sq;
    __syncthreads();
    if (t < 32) {
        float m = 0.f, q = 0.f;
#pragma unroll
        for (int j = 0; j < 8; ++j) { m += Sm[j][t]; q += Sq[j][t]; }
        float mu = m * (1.0f / EMBED);
        float var = q * (1.0f / EMBED) - mu * mu;
        muA[b * S_LEN + s0 + t] = mu;
        rsA[b * S_LEN + s0 + t] = rsqrtf(var + 1e-5f);
    }
}

// ---------------------------------------------------------------------------
// LN transpose+normalize: x[b,c,s] f32 -> xn[b,s,c] bf16 (32x32 LDS tile)
// ---------------------------------------------------------------------------
__global__ __launch_bounds__(256) void ln_tr_kernel(const float* __restrict__ x,
                                                    const float* __restrict__ muA,
                                                    const float* __restrict__ rsA,
                                                    const float* __restrict__ gamma,
                                                    const float* __restrict__ beta,
                                                    bf16_t* __restrict__ xn) {
    __shared__ float T[32][33];
    int tx = threadIdx.x & 31, ty = threadIdx.x >> 5;
    int b = blockIdx.z, c0 = blockIdx.y * 32, s0 = blockIdx.x * 32;
#pragma unroll
    for (int i = 0; i < 4; ++i) {
        int cr = ty + i * 8;
        T[cr][tx] = x[((size_t)b * EMBED + c0 + cr) * S_LEN + s0 + tx];
    }
    __syncthreads();
    float g = gamma[c0 + tx], be = beta[c0 + tx];
#pragma unroll
    for (int i = 0; i < 4; ++i) {
        int sr = ty + i * 8;
        float mu = muA[b * S_LEN + s0 + sr];
        float rs = rsA[b * S_LEN + s0 + sr];
        xn[((size_t)b * S_LEN + s0 + sr) * EMBED + c0 + tx] =
            f2bf((T[tx][sr] - mu) * rs * g + be);
    }
}

// ---------------------------------------------------------------------------
// GEMM  Y[m, col] = sum_k X[m,k]*W[col,k] + bias[col]
// block: 128 rows x 64 cols, K=512 staged whole in LDS (stride 520 pad).
// wave: 32 rows x 64 cols via 2 A-frags, 4 B-frags, 8 MFMA / 32-K step.
// ---------------------------------------------------------------------------
__global__ __launch_bounds__(256) void gemm_kernel(const bf16_t* __restrict__ X,
                                                   const bf16_t* __restrict__ W,
                                                   const float* __restrict__ bias,
                                                   bf16_t* __restrict__ Y, int ldY) {
    __shared__ __align__(16) bf16_t Wl[64 * 520];
    int t = threadIdx.x;
    int col0 = blockIdx.y * 64, row0 = blockIdx.x * 128;
    {   // stage W tile: 64 rows x 512, each thread one quarter-row (128 elems)
        int row = t >> 2, seg = (t & 3) * 128;
        const bf16_t* src = W + (size_t)(col0 + row) * EMBED + seg;
        bf16_t* dst = &Wl[row * 520 + seg];
#pragma unroll
        for (int i = 0; i < 16; ++i)
            *(bf16x8*)(dst + i * 8) = *(const bf16x8*)(src + i * 8);
    }
    __syncthreads();
    int lane = t & 63, w = t >> 6, g = lane >> 4, n16 = lane & 15;
    int rw0 = row0 + w * 32;
    const bf16_t* xr0 = X + (size_t)(rw0 + n16) * EMBED + g * 8;
    const bf16_t* xr1 = xr0 + (size_t)16 * EMBED;
    floatx4 acc[2][4] = {};
    for (int ks = 0; ks < 16; ++ks) {
        int k32 = ks * 32;
        bf16x8 a0 = *(const bf16x8*)(xr0 + k32);
        bf16x8 a1 = *(const bf16x8*)(xr1 + k32);
#pragma unroll
        for (int nt = 0; nt < 4; ++nt) {
            bf16x8 bfr = *(const bf16x8*)(&Wl[(nt * 16 + n16) * 520 + k32 + g * 8]);
            acc[0][nt] = MFMA16(a0, bfr, acc[0][nt]);
            acc[1][nt] = MFMA16(a1, bfr, acc[1][nt]);
        }
    }
#pragma unroll
    for (int ar = 0; ar < 2; ++ar)
#pragma unroll
        for (int nt = 0; nt < 4; ++nt) {
            int col = col0 + nt * 16 + n16;
            float bv = bias[col];
#pragma unroll
            for (int r = 0; r < 4; ++r) {
                int row = rw0 + ar * 16 + g * 4 + r;
                Y[(size_t)row * ldY + col] = f2bf(acc[ar][nt][r] + bv);
            }
        }
}

// ---------------------------------------------------------------------------
// V transpose: qkv[b, s, 1024 + c] (stride 1536) -> vtb[b, c, s]
// ---------------------------------------------------------------------------
__global__ __launch_bounds__(256) void vtr_kernel(const bf16_t* __restrict__ src,
                                                  bf16_t* __restrict__ dst) {
    __shared__ bf16_t T[32][33];
    int tx = threadIdx.x & 31, ty = threadIdx.x >> 5;
    int b = blockIdx.z, c0 = blockIdx.y * 32, s0 = blockIdx.x * 32;
#pragma unroll
    for (int i = 0; i < 4; ++i) {
        int sr = ty + i * 8;
        T[sr][tx] = src[((size_t)b * S_LEN + s0 + sr) * LDQ + 1024 + c0 + tx];
    }
    __syncthreads();
#pragma unroll
    for (int i = 0; i < 4; ++i) {
        int cr = ty + i * 8;
        dst[((size_t)b * EMBED + c0 + cr) * S_LEN + s0 + tx] = T[tx][cr];
    }
}

// ---------------------------------------------------------------------------
// Flash attention, barrier-free.  1D grid: bid&63 = (b,h) [XCD locality],
// bid>>6 = qt.  4 waves x 16 q-rows; 64 keys/iter; K and V^T fragments
// straight from global (L2); P via per-wave f32 LDS (stride 68, no conflicts).
// ---------------------------------------------------------------------------
__global__ __launch_bounds__(256) void attn_kernel(const bf16_t* __restrict__ qkv,
                                                   const bf16_t* __restrict__ vt,
                                                   bf16_t* __restrict__ o) {
    __shared__ __align__(16) float Pl[4][16 * 68];
    int bid = blockIdx.x;
    int bh = bid & 63, qt = bid >> 6;
    int b = bh >> 3, h = bh & 7;
    int t = threadIdx.x, w = t >> 6, lane = t & 63, g = lane >> 4, n16 = lane & 15;
    size_t baseQ = (size_t)b * S_LEN * LDQ + h * HD;
    size_t baseV = ((size_t)b * EMBED + h * HD) * S_LEN;
    size_t baseO = (size_t)b * S_LEN * EMBED + h * HD;
    int qr0 = qt * 64 + w * 16;

    // Q fragments, pre-scaled by 1/sqrt(64)=0.125 (exact in bf16)
    const bf16_t* qp = qkv + baseQ + (size_t)(qr0 + n16) * LDQ + g * 8;
    bf16x8 qf0 = *(const bf16x8*)(qp);
    bf16x8 qf1 = *(const bf16x8*)(qp + 32);
#pragma unroll
    for (int j = 0; j < 8; ++j) {
        qf0[j] = f2bf(bf2f(qf0[j]) * 0.125f);
        qf1[j] = f2bf(bf2f(qf1[j]) * 0.125f);
    }
    const bf16_t* kbase = qkv + baseQ + 512;

    float m_i[4] = {-1e30f, -1e30f, -1e30f, -1e30f};
    float l_i[4] = {0.f, 0.f, 0.f, 0.f};
    floatx4 oacc[4] = {};
    float* PLw = &Pl[w][0];

    for (int kt = 0; kt < S_LEN; kt += 64) {
        // ---- scores for 16 q-rows x 64 keys ----
        floatx4 s[4] = {};
#pragma unroll
        for (int kb = 0; kb < 4; ++kb) {
            const bf16_t* kp = kbase + (size_t)(kt + kb * 16 + n16) * LDQ + g * 8;
            bf16x8 k0 = *(const bf16x8*)(kp);
            bf16x8 k1 = *(const bf16x8*)(kp + 32);
            s[kb] = MFMA16(qf0, k0, s[kb]);
            s[kb] = MFMA16(qf1, k1, s[kb]);
        }
        // ---- online softmax (row = g*4+r; reduce over 16 key-lanes) ----
        float al[4];
#pragma unroll
        for (int r = 0; r < 4; ++r) {
            float mx = fmaxf(fmaxf(s[0][r], s[1][r]), fmaxf(s[2][r], s[3][r]));
#pragma unroll
            for (int off = 1; off <= 8; off <<= 1) mx = fmaxf(mx, __shfl_xor(mx, off));
            float mn = fmaxf(m_i[r], mx);
            float e0 = __expf(s[0][r] - mn), e1 = __expf(s[1][r] - mn);
            float e2 = __expf(s[2][r] - mn), e3 = __expf(s[3][r] - mn);
            float rs = (e0 + e1) + (e2 + e3);
#pragma unroll
            for (int off = 1; off <= 8; off <<= 1) rs += __shfl_xor(rs, off);
            float a = __expf(m_i[r] - mn);
            l_i[r] = l_i[r] * a + rs;
            m_i[r] = mn;
            al[r] = a;
            int rowoff = (g * 4 + r) * 68;
            PLw[rowoff + n16]      = e0;
            PLw[rowoff + 16 + n16] = e1;
            PLw[rowoff + 32 + n16] = e2;
            PLw[rowoff + 48 + n16] = e3;
        }
#pragma unroll
        for (int nt = 0; nt < 4; ++nt)
#pragma unroll
            for (int r = 0; r < 4; ++r) oacc[nt][r] *= al[r];

        // ---- P: C-layout -> A-fragments (per-wave LDS, in-order DS pipe) ----
        floatx4 p0 = *(const floatx4*)&PLw[n16 * 68 + g * 8];
        floatx4 p1 = *(const floatx4*)&PLw[n16 * 68 + g * 8 + 4];
        floatx4 p2 = *(const floatx4*)&PLw[n16 * 68 + g * 8 + 32];
        floatx4 p3 = *(const floatx4*)&PLw[n16 * 68 + g * 8 + 36];
        bf16x8 pfa = pack8(p0, p1);
        bf16x8 pfb = pack8(p2, p3);
        // ---- O += P V ----
#pragma unroll
        for (int dt = 0; dt < 4; ++dt) {
            const bf16_t* vp = vt + baseV + (size_t)(dt * 16 + n16) * S_LEN + kt + g * 8;
            bf16x8 v0 = *(const bf16x8*)(vp);
            bf16x8 v1 = *(const bf16x8*)(vp + 32);
            oacc[dt] = MFMA16(pfa, v0, oacc[dt]);
            oacc[dt] = MFMA16(pfb, v1, oacc[dt]);
        }
    }
    // ---- epilogue ----
    float rl[4];
#pragma unroll
    for (int r = 0; r < 4; ++r) rl[r] = 1.0f / l_i[r];
#pragma unroll
    for (int dt = 0; dt < 4; ++dt)
#pragma unroll
        for (int r = 0; r < 4; ++r) {
            int row = qr0 + g * 4 + r;
            o[baseO + (size_t)row * EMBED + dt * 16 + n16] = f2bf(oacc[dt][r] * rl[r]);
        }
}

// ---------------------------------------------------------------------------
// out[b,c,s] = tmp[b,s,c](bf16, stride 512) + x[b,c,s](f32) -> f32
// ---------------------------------------------------------------------------
__global__ __launch_bounds__(256) void trres_kernel(const bf16_t* __restrict__ tmp,
                                                    const float* __restrict__ x,
                                                    float* __restrict__ out) {
    __shared__ float T[32][33];
    int tx = threadIdx.x & 31, ty = threadIdx.x >> 5;
    int b = blockIdx.z, c0 = blockIdx.y * 32, s0 = blockIdx.x * 32;
#pragma unroll
    for (int i = 0; i < 4; ++i) {
        int sr = ty + i * 8;
        T[sr][tx] = bf2f(tmp[((size_t)b * S_LEN + s0 + sr) * EMBED + c0 + tx]);
    }
    __syncthreads();
#pragma unroll
    for (int i = 0; i < 4; ++i) {
        int cr = ty + i * 8;
        size_t oi = ((size_t)b * EMBED + c0 + cr) * S_LEN + s0 + tx;
        out[oi] = T[tx][cr] + x[oi];
    }
}

extern "C" void kernel_launch(void* const* d_in, const int* in_sizes, int n_in,
                              void* d_out, int out_size, void* d_ws, size_t ws_size,
                              hipStream_t stream) {
    const float* x     = (const float*)d_in[0];
    const float* Wq    = (const float*)d_in[1];
    const float* bq    = (const float*)d_in[2];
    const float* Wk    = (const float*)d_in[3];
    const float* bk    = (const float*)d_in[4];
    const float* Wv    = (const float*)d_in[5];
    const float* bv    = (const float*)d_in[6];
    const float* Wo    = (const float*)d_in[7];
    const float* bo    = (const float*)d_in[8];
    const float* gamma = (const float*)d_in[9];
    const float* beta  = (const float*)d_in[10];
    float* out = (float*)d_out;

    // d_out (16.78 MB) hosts temporaries that all die before trres writes out:
    char* ob = (char*)d_out;
    bf16_t* vtb      = (bf16_t*)(ob);              // [0, 8M)   V^T [b][c][s]
    bf16_t* wqkv     = (bf16_t*)(ob + 8388608);    // [8M, 9.5M) packed [1536][512]
    bf16_t* wob      = (bf16_t*)(ob + 9961472);    // 512 KB
    float*  bias1536 = (float*)(ob + 10485760);    // 6 KB
    float*  muA      = (float*)(ob + 10491904);    // 32 KB
    float*  rsA      = (float*)(ob + 10524672);    // 32 KB

    char* ws = (char*)d_ws;                        // 32 MB used
    bf16_t* xn  = (bf16_t*)ws;                     // [0,8M): xn, later attn-out
    bf16_t* qkv = (bf16_t*)(ws + 8388608);         // [8M,32M): packed qkv, later tb
    bf16_t* ab  = xn;
    bf16_t* tb  = qkv;

    cvt_kernel<<<dim3(128), 256, 0, stream>>>(Wq, wqkv);
    cvt_kernel<<<dim3(128), 256, 0, stream>>>(Wk, wqkv + 262144);
    cvt_kernel<<<dim3(128), 256, 0, stream>>>(Wv, wqkv + 524288);
    cvt_kernel<<<dim3(128), 256, 0, stream>>>(Wo, wob);
    pack_bias_kernel<<<dim3(1), 512, 0, stream>>>(bq, bk, bv, bias1536);
    ln_stats_kernel<<<dim3(256), 256, 0, stream>>>(x, muA, rsA);
    ln_tr_kernel<<<dim3(32, 16, 8), 256, 0, stream>>>(x, muA, rsA, gamma, beta, xn);
    gemm_kernel<<<dim3(64, 24), 256, 0, stream>>>(xn, wqkv, bias1536, qkv, LDQ);
    vtr_kernel<<<dim3(32, 16, 8), 256, 0, stream>>>(qkv, vtb);
    attn_kernel<<<dim3(1024), 256, 0, stream>>>(qkv, vtb, ab);
    gemm_kernel<<<dim3(64, 8), 256, 0, stream>>>(ab, wob, bo, tb, EMBED);
    trres_kernel<<<dim3(32, 16, 8), 256, 0, stream>>>(tb, x, out);
}

// Round 4
// 284.772 us; speedup vs baseline: 1.3506x; 1.0075x over previous
//
#include <hip/hip_runtime.h>
#include <hip/hip_bf16.h>

typedef __bf16 bf16_t;
typedef __bf16 bf16x8 __attribute__((ext_vector_type(8)));
typedef float floatx4 __attribute__((ext_vector_type(4)));

#define EMBED 512
#define S_LEN 1024
#define NH 8
#define HD 64

#define MFMA16(a, b, c) __builtin_amdgcn_mfma_f32_16x16x32_bf16(a, b, c, 0, 0, 0)

static __device__ __forceinline__ bf16_t f2bf(float f) {
    unsigned int x = __builtin_bit_cast(unsigned int, f);
    unsigned int lsb = (x >> 16) & 1u;
    x += 0x7fffu + lsb;                 // RNE
    unsigned short u = (unsigned short)(x >> 16);
    return __builtin_bit_cast(bf16_t, u);
}
static __device__ __forceinline__ float bf2f(bf16_t v) {
    unsigned short u = __builtin_bit_cast(unsigned short, v);
    unsigned int x = ((unsigned int)u) << 16;
    return __builtin_bit_cast(float, x);
}
// pack two f32 -> one u32 holding two bf16 (truncate; P in [0,1])
static __device__ __forceinline__ unsigned int pack2(float lo, float hi) {
    return (__builtin_bit_cast(unsigned int, lo) >> 16) |
           (__builtin_bit_cast(unsigned int, hi) & 0xFFFF0000u);
}

// ---------------------------------------------------------------------------
// f32 -> bf16 conversion for the 4 weight matrices in one launch
// ---------------------------------------------------------------------------
__global__ __launch_bounds__(256) void cvt4_kernel(const float* __restrict__ s0,
                                                   const float* __restrict__ s1,
                                                   const float* __restrict__ s2,
                                                   const float* __restrict__ s3,
                                                   bf16_t* __restrict__ d0,
                                                   bf16_t* __restrict__ d1,
                                                   bf16_t* __restrict__ d2,
                                                   bf16_t* __restrict__ d3) {
    const float* s; bf16_t* d;
    switch (blockIdx.y) {
        case 0:  s = s0; d = d0; break;
        case 1:  s = s1; d = d1; break;
        case 2:  s = s2; d = d2; break;
        default: s = s3; d = d3; break;
    }
    int i = (blockIdx.x * 256 + threadIdx.x) * 8;
#pragma unroll
    for (int j = 0; j < 8; ++j) d[i + j] = f2bf(s[i + j]);
}

// ---------------------------------------------------------------------------
// LN stats: per (b,s) mean/rstd over c.  Coalesced reads along s.
// ---------------------------------------------------------------------------
__global__ __launch_bounds__(256) void ln_stats_kernel(const float* __restrict__ x,
                                                       float* __restrict__ muA,
                                                       float* __restrict__ rsA) {
    int bid = blockIdx.x;
    int b = bid >> 5, s0 = (bid & 31) * 32;
    int t = threadIdx.x, tc = t >> 5, ts = t & 31;
    const float* xp = x + (size_t)b * EMBED * S_LEN + s0 + ts;
    float sm = 0.f, sq = 0.f;
    for (int i = 0; i < 64; ++i) {
        float v = xp[(size_t)(tc * 64 + i) * S_LEN];
        sm += v; sq += v * v;
    }
    __shared__ float Sm[8][32], Sq[8][32];
    Sm[tc][ts] = sm; Sq[tc][ts] = sq;
    __syncthreads();
    if (t < 32) {
        float m = 0.f, q = 0.f;
#pragma unroll
        for (int j = 0; j < 8; ++j) { m += Sm[j][t]; q += Sq[j][t]; }
        float mu = m * (1.0f / EMBED);
        float var = q * (1.0f / EMBED) - mu * mu;
        muA[b * S_LEN + s0 + t] = mu;
        rsA[b * S_LEN + s0 + t] = rsqrtf(var + 1e-5f);
    }
}

// ---------------------------------------------------------------------------
// LN transpose+normalize: x[b,c,s] f32 -> xn[b,s,c] bf16 (32x32 LDS tile)
// ---------------------------------------------------------------------------
__global__ __launch_bounds__(256) void ln_tr_kernel(const float* __restrict__ x,
                                                    const float* __restrict__ muA,
                                                    const float* __restrict__ rsA,
                                                    const float* __restrict__ gamma,
                                                    const float* __restrict__ beta,
                                                    bf16_t* __restrict__ xn) {
    __shared__ float T[32][33];
    int tx = threadIdx.x & 31, ty = threadIdx.x >> 5;
    int b = blockIdx.z, c0 = blockIdx.y * 32, s0 = blockIdx.x * 32;
#pragma unroll
    for (int i = 0; i < 4; ++i) {
        int cr = ty + i * 8;
        T[cr][tx] = x[((size_t)b * EMBED + c0 + cr) * S_LEN + s0 + tx];
    }
    __syncthreads();
    float g = gamma[c0 + tx], be = beta[c0 + tx];
#pragma unroll
    for (int i = 0; i < 4; ++i) {
        int sr = ty + i * 8;
        float mu = muA[b * S_LEN + s0 + sr];
        float rs = rsA[b * S_LEN + s0 + sr];
        xn[((size_t)b * S_LEN + s0 + sr) * EMBED + c0 + tx] =
            f2bf((T[tx][sr] - mu) * rs * g + be);
    }
}

// ---------------------------------------------------------------------------
// Act-stationary GEMM  Y[m, col] = sum_k X[m,k]*W[col,k] + bias[col]
// (QK projection: W = packed [1024][512], bias split b0/b1 at col 512)
// block: 128 rows x 64 cols; W-tile (64x512, pad 520) in LDS; A direct.
// ---------------------------------------------------------------------------
__global__ __launch_bounds__(256) void gemm_kernel(const bf16_t* __restrict__ X,
                                                   const bf16_t* __restrict__ W,
                                                   const float* __restrict__ b0,
                                                   const float* __restrict__ b1,
                                                   bf16_t* __restrict__ Y, int ldY) {
    __shared__ __align__(16) bf16_t Wl[64 * 520];
    int t = threadIdx.x;
    int col0 = blockIdx.y * 64, row0 = blockIdx.x * 128;
    {
        int row = t >> 2, seg = (t & 3) * 128;
        const bf16_t* src = W + (size_t)(col0 + row) * EMBED + seg;
        bf16_t* dst = &Wl[row * 520 + seg];
#pragma unroll
        for (int i = 0; i < 16; ++i)
            *(bf16x8*)(dst + i * 8) = *(const bf16x8*)(src + i * 8);
    }
    __syncthreads();
    int lane = t & 63, w = t >> 6, g = lane >> 4, n16 = lane & 15;
    int rw0 = row0 + w * 32;
    const bf16_t* xr0 = X + (size_t)(rw0 + n16) * EMBED + g * 8;
    const bf16_t* xr1 = xr0 + (size_t)16 * EMBED;
    floatx4 acc[2][4] = {};
    for (int ks = 0; ks < 16; ++ks) {
        int k32 = ks * 32;
        bf16x8 a0 = *(const bf16x8*)(xr0 + k32);
        bf16x8 a1 = *(const bf16x8*)(xr1 + k32);
#pragma unroll
        for (int nt = 0; nt < 4; ++nt) {
            bf16x8 bfr = *(const bf16x8*)(&Wl[(nt * 16 + n16) * 520 + k32 + g * 8]);
            acc[0][nt] = MFMA16(a0, bfr, acc[0][nt]);
            acc[1][nt] = MFMA16(a1, bfr, acc[1][nt]);
        }
    }
#pragma unroll
    for (int ar = 0; ar < 2; ++ar)
#pragma unroll
        for (int nt = 0; nt < 4; ++nt) {
            int col = col0 + nt * 16 + n16;
            float bv = (col < 512) ? b0[col] : b1[col - 512];
#pragma unroll
            for (int r = 0; r < 4; ++r) {
                int row = rw0 + ar * 16 + g * 4 + r;
                Y[(size_t)row * ldY + col] = f2bf(acc[ar][nt][r] + bv);
            }
        }
}

// ---------------------------------------------------------------------------
// Weight-stationary GEMM, V-projection transposed output:
// vt[b][m][n] = sum_k Wv[m][k] * xn[b][n][k] + bv[m]   (m=channel, n=token)
// Act tile (64 tokens x 512, pad 520) staged in LDS; W rows streamed direct.
// ---------------------------------------------------------------------------
__global__ __launch_bounds__(256) void wsgemm_vt_kernel(const bf16_t* __restrict__ Wb,
                                                        const bf16_t* __restrict__ act,
                                                        const float* __restrict__ bias,
                                                        bf16_t* __restrict__ vtb) {
    __shared__ __align__(16) bf16_t Al[64 * 520];
    int b = blockIdx.z, n0 = blockIdx.x * 64, m0 = blockIdx.y * 128;
    int t = threadIdx.x;
    {
        int row = t >> 2, seg = (t & 3) * 128;
        const bf16_t* src = act + ((size_t)b * S_LEN + n0 + row) * EMBED + seg;
        bf16_t* dst = &Al[row * 520 + seg];
#pragma unroll
        for (int i = 0; i < 16; ++i)
            *(bf16x8*)(dst + i * 8) = *(const bf16x8*)(src + i * 8);
    }
    __syncthreads();
    int lane = t & 63, w = t >> 6, g = lane >> 4, n16 = lane & 15;
    int mw = m0 + w * 32;
    const bf16_t* wr0 = Wb + (size_t)(mw + n16) * EMBED + g * 8;
    const bf16_t* wr1 = wr0 + (size_t)16 * EMBED;
    floatx4 acc[2][4] = {};
    for (int ks = 0; ks < 16; ++ks) {
        int k32 = ks * 32;
        bf16x8 a0 = *(const bf16x8*)(wr0 + k32);
        bf16x8 a1 = *(const bf16x8*)(wr1 + k32);
#pragma unroll
        for (int nt = 0; nt < 4; ++nt) {
            bf16x8 bfr = *(const bf16x8*)(&Al[(nt * 16 + n16) * 520 + k32 + g * 8]);
            acc[0][nt] = MFMA16(a0, bfr, acc[0][nt]);
            acc[1][nt] = MFMA16(a1, bfr, acc[1][nt]);
        }
    }
#pragma unroll
    for (int ar = 0; ar < 2; ++ar)
#pragma unroll
        for (int r = 0; r < 4; ++r) {
            int row = mw + ar * 16 + g * 4 + r;
            float bv = bias[row];
#pragma unroll
            for (int nt = 0; nt < 4; ++nt) {
                int col = n0 + nt * 16 + n16;
                vtb[((size_t)b * EMBED + row) * S_LEN + col] = f2bf(acc[ar][nt][r] + bv);
            }
        }
}

// ---------------------------------------------------------------------------
// Weight-stationary GEMM, O-projection + bias + residual, NCHW f32 output:
// out[b][m][n] = sum_k Wo[m][k] * ab[b][n][k] + bo[m] + x[b][m][n]
// ---------------------------------------------------------------------------
__global__ __launch_bounds__(256) void wsgemm_out_kernel(const bf16_t* __restrict__ Wb,
                                                         const bf16_t* __restrict__ act,
                                                         const float* __restrict__ bias,
                                                         const float* __restrict__ xres,
                                                         float* __restrict__ out) {
    __shared__ __align__(16) bf16_t Al[64 * 520];
    int b = blockIdx.z, n0 = blockIdx.x * 64, m0 = blockIdx.y * 128;
    int t = threadIdx.x;
    {
        int row = t >> 2, seg = (t & 3) * 128;
        const bf16_t* src = act + ((size_t)b * S_LEN + n0 + row) * EMBED + seg;
        bf16_t* dst = &Al[row * 520 + seg];
#pragma unroll
        for (int i = 0; i < 16; ++i)
            *(bf16x8*)(dst + i * 8) = *(const bf16x8*)(src + i * 8);
    }
    __syncthreads();
    int lane = t & 63, w = t >> 6, g = lane >> 4, n16 = lane & 15;
    int mw = m0 + w * 32;
    const bf16_t* wr0 = Wb + (size_t)(mw + n16) * EMBED + g * 8;
    const bf16_t* wr1 = wr0 + (size_t)16 * EMBED;
    floatx4 acc[2][4] = {};
    for (int ks = 0; ks < 16; ++ks) {
        int k32 = ks * 32;
        bf16x8 a0 = *(const bf16x8*)(wr0 + k32);
        bf16x8 a1 = *(const bf16x8*)(wr1 + k32);
#pragma unroll
        for (int nt = 0; nt < 4; ++nt) {
            bf16x8 bfr = *(const bf16x8*)(&Al[(nt * 16 + n16) * 520 + k32 + g * 8]);
            acc[0][nt] = MFMA16(a0, bfr, acc[0][nt]);
            acc[1][nt] = MFMA16(a1, bfr, acc[1][nt]);
        }
    }
#pragma unroll
    for (int ar = 0; ar < 2; ++ar)
#pragma unroll
        for (int r = 0; r < 4; ++r) {
            int row = mw + ar * 16 + g * 4 + r;
            float bv = bias[row];
#pragma unroll
            for (int nt = 0; nt < 4; ++nt) {
                int col = n0 + nt * 16 + n16;
                size_t oi = ((size_t)b * EMBED + row) * S_LEN + col;
                out[oi] = acc[ar][nt][r] + bv + xres[oi];
            }
        }
}

// ---------------------------------------------------------------------------
// Flash attention, transposed-softmax, barrier-free.
// grid: bid&63=(b,h) [XCD L2 locality], bid>>6=qt; 4 waves x 16 q.
// S^T = K-rows x Q-rows MFMA -> each lane owns one q-col, 16 key-scores in
// regs -> in-register max/sum + 2 shfls.  P^T through tiny per-wave LDS
// (bf16, 4xb64 write + 2xb128 read).  O^T = V^T-rows x P^T-rows MFMA.
// ---------------------------------------------------------------------------
__global__ __launch_bounds__(256) void attn_kernel(const bf16_t* __restrict__ qk,
                                                   const bf16_t* __restrict__ vt,
                                                   bf16_t* __restrict__ o) {
    __shared__ __align__(16) unsigned int Pl[4][16 * 36];  // per-wave P^T [16 q][72 bf16]
    int bid = blockIdx.x;
    int bh = bid & 63, qt = bid >> 6;
    int b = bh >> 3, h = bh & 7;
    int t = threadIdx.x, w = t >> 6, lane = t & 63, g = lane >> 4, n16 = lane & 15;
    size_t baseQK = (size_t)b << 20;                       // b*1024*1024
    size_t baseV  = ((size_t)b * EMBED + h * HD) * S_LEN;
    int q_glob = qt * 64 + w * 16 + n16;

    const bf16_t* qp = qk + baseQK + (size_t)q_glob * 1024 + h * HD + g * 8;
    bf16x8 qf0 = *(const bf16x8*)(qp);
    bf16x8 qf1 = *(const bf16x8*)(qp + 32);
#pragma unroll
    for (int j = 0; j < 8; ++j) {                          // pre-scale by 1/sqrt(64)
        qf0[j] = f2bf(bf2f(qf0[j]) * 0.125f);
        qf1[j] = f2bf(bf2f(qf1[j]) * 0.125f);
    }
    const bf16_t* kbase = qk + baseQK + 512 + h * HD;

    float m_i = -1e30f, l_i = 0.f;
    floatx4 oacc[4] = {};
    unsigned int* PLw = &Pl[w][0];

    for (int kt = 0; kt < S_LEN; kt += 64) {
        // ---- S^T: 64 keys (rows) x 16 q (cols) ----
        floatx4 s[4] = {};
#pragma unroll
        for (int kb = 0; kb < 4; ++kb) {
            const bf16_t* kp = kbase + (size_t)(kt + kb * 16 + n16) * 1024 + g * 8;
            bf16x8 k0 = *(const bf16x8*)(kp);
            bf16x8 k1 = *(const bf16x8*)(kp + 32);
            s[kb] = MFMA16(k0, qf0, s[kb]);
            s[kb] = MFMA16(k1, qf1, s[kb]);
        }
        // ---- softmax: lane owns q=n16, 16 key-scores in regs ----
        float mx = -1e30f;
#pragma unroll
        for (int kb = 0; kb < 4; ++kb)
#pragma unroll
            for (int r = 0; r < 4; ++r) mx = fmaxf(mx, s[kb][r]);
        mx = fmaxf(mx, __shfl_xor(mx, 16));
        mx = fmaxf(mx, __shfl_xor(mx, 32));
        float mn = fmaxf(m_i, mx);
        float rs = 0.f;
#pragma unroll
        for (int kb = 0; kb < 4; ++kb)
#pragma unroll
            for (int r = 0; r < 4; ++r) {
                s[kb][r] = __expf(s[kb][r] - mn);
                rs += s[kb][r];
            }
        rs += __shfl_xor(rs, 16);
        rs += __shfl_xor(rs, 32);
        float al = __expf(m_i - mn);
        l_i = l_i * al + rs;
        m_i = mn;
#pragma unroll
        for (int dt = 0; dt < 4; ++dt)
#pragma unroll
            for (int r = 0; r < 4; ++r) oacc[dt][r] *= al;

        // ---- P^T -> per-wave LDS (bf16 [q][72]) -> B-fragments ----
#pragma unroll
        for (int kb = 0; kb < 4; ++kb) {
            uint2 pr;
            pr.x = pack2(s[kb][0], s[kb][1]);
            pr.y = pack2(s[kb][2], s[kb][3]);
            *(uint2*)&PLw[n16 * 36 + kb * 8 + g * 2] = pr;
        }
        uint4 u0 = *(const uint4*)&PLw[n16 * 36 + g * 4];
        uint4 u1 = *(const uint4*)&PLw[n16 * 36 + 16 + g * 4];
        bf16x8 pf0 = __builtin_bit_cast(bf16x8, u0);
        bf16x8 pf1 = __builtin_bit_cast(bf16x8, u1);

        // ---- O^T += V^T P^T ----
#pragma unroll
        for (int dt = 0; dt < 4; ++dt) {
            const bf16_t* vp = vt + baseV + (size_t)(dt * 16 + n16) * S_LEN + kt + g * 8;
            bf16x8 v0 = *(const bf16x8*)(vp);
            bf16x8 v1 = *(const bf16x8*)(vp + 32);
            oacc[dt] = MFMA16(v0, pf0, oacc[dt]);
            oacc[dt] = MFMA16(v1, pf1, oacc[dt]);
        }
    }
    // ---- epilogue: lane q=n16, d=dt*16+g*4+r -> ab[b*1024+q][h*64+d] ----
    float rl = 1.0f / l_i;
    size_t orow = ((size_t)b * S_LEN + q_glob) * EMBED + h * HD;
#pragma unroll
    for (int dt = 0; dt < 4; ++dt) {
        uint2 pr;
        pr.x = pack2(oacc[dt][0] * rl, oacc[dt][1] * rl);
        pr.y = pack2(oacc[dt][2] * rl, oacc[dt][3] * rl);
        *(uint2*)(o + orow + dt * 16 + g * 4) = pr;
    }
}

extern "C" void kernel_launch(void* const* d_in, const int* in_sizes, int n_in,
                              void* d_out, int out_size, void* d_ws, size_t ws_size,
                              hipStream_t stream) {
    const float* x     = (const float*)d_in[0];
    const float* Wq    = (const float*)d_in[1];
    const float* bq    = (const float*)d_in[2];
    const float* Wk    = (const float*)d_in[3];
    const float* bk    = (const float*)d_in[4];
    const float* Wv    = (const float*)d_in[5];
    const float* bv    = (const float*)d_in[6];
    const float* Wo    = (const float*)d_in[7];
    const float* bo    = (const float*)d_in[8];
    const float* gamma = (const float*)d_in[9];
    const float* beta  = (const float*)d_in[10];
    float* out = (float*)d_out;

    char* ws = (char*)d_ws;                        // ~26.1 MB used
    bf16_t* xn   = (bf16_t*)ws;                    // [0,8M); reused as attn-out
    bf16_t* qkb  = (bf16_t*)(ws + 8388608);        // [8M,24M) packed QK [8192][1024]
    bf16_t* wqk  = (bf16_t*)(ws + 25165824);       // 1 MB packed [1024][512]
    bf16_t* wv   = (bf16_t*)(ws + 26214400);       // 512 KB
    bf16_t* wo   = (bf16_t*)(ws + 26738688);       // 512 KB
    float*  muA  = (float*)(ws + 27262976);        // 32 KB
    float*  rsA  = (float*)(ws + 27295744);        // 32 KB
    bf16_t* ab   = xn;

    // vt lives in d_out's lower 8 MB: dead before wsgemm_out writes d_out
    bf16_t* vtb = (bf16_t*)d_out;

    cvt4_kernel<<<dim3(128, 4), 256, 0, stream>>>(Wq, Wk, Wv, Wo,
                                                  wqk, wqk + 262144, wv, wo);
    ln_stats_kernel<<<dim3(256), 256, 0, stream>>>(x, muA, rsA);
    ln_tr_kernel<<<dim3(32, 16, 8), 256, 0, stream>>>(x, muA, rsA, gamma, beta, xn);
    gemm_kernel<<<dim3(64, 16), 256, 0, stream>>>(xn, wqk, bq, bk, qkb, 1024);
    wsgemm_vt_kernel<<<dim3(16, 4, 8), 256, 0, stream>>>(wv, xn, bv, vtb);
    attn_kernel<<<dim3(1024), 256, 0, stream>>>(qkb, vtb, ab);
    wsgemm_out_kernel<<<dim3(16, 4, 8), 256, 0, stream>>>(wo, ab, bo, x, out);
}

// Round 5
// 260.069 us; speedup vs baseline: 1.4789x; 1.0950x over previous
//
#include <hip/hip_runtime.h>
#include <hip/hip_bf16.h>

typedef __bf16 bf16_t;
typedef __bf16 bf16x8 __attribute__((ext_vector_type(8)));
typedef float floatx4 __attribute__((ext_vector_type(4)));

#define EMBED 512
#define S_LEN 1024
#define NH 8
#define HD 64
#define LDK 1056   // padded row stride of packed QK buffer (breaks 2KB L2 camping)
#define LDV 1088   // padded row stride of V^T buffer

#define MFMA16(a, b, c) __builtin_amdgcn_mfma_f32_16x16x32_bf16(a, b, c, 0, 0, 0)

static __device__ __forceinline__ bf16_t f2bf(float f) {
    unsigned int x = __builtin_bit_cast(unsigned int, f);
    unsigned int lsb = (x >> 16) & 1u;
    x += 0x7fffu + lsb;                 // RNE
    unsigned short u = (unsigned short)(x >> 16);
    return __builtin_bit_cast(bf16_t, u);
}
static __device__ __forceinline__ float bf2f(bf16_t v) {
    unsigned short u = __builtin_bit_cast(unsigned short, v);
    unsigned int x = ((unsigned int)u) << 16;
    return __builtin_bit_cast(float, x);
}
// pack two f32 -> one u32 holding two bf16 (truncate; P in [0,1])
static __device__ __forceinline__ unsigned int pack2(float lo, float hi) {
    return (__builtin_bit_cast(unsigned int, lo) >> 16) |
           (__builtin_bit_cast(unsigned int, hi) & 0xFFFF0000u);
}

// ---------------------------------------------------------------------------
// f32 -> bf16 conversion for the 4 weight matrices in one launch
// ---------------------------------------------------------------------------
__global__ __launch_bounds__(256) void cvt4_kernel(const float* __restrict__ s0,
                                                   const float* __restrict__ s1,
                                                   const float* __restrict__ s2,
                                                   const float* __restrict__ s3,
                                                   bf16_t* __restrict__ d0,
                                                   bf16_t* __restrict__ d1,
                                                   bf16_t* __restrict__ d2,
                                                   bf16_t* __restrict__ d3) {
    const float* s; bf16_t* d;
    switch (blockIdx.y) {
        case 0:  s = s0; d = d0; break;
        case 1:  s = s1; d = d1; break;
        case 2:  s = s2; d = d2; break;
        default: s = s3; d = d3; break;
    }
    int i = (blockIdx.x * 256 + threadIdx.x) * 8;
#pragma unroll
    for (int j = 0; j < 8; ++j) d[i + j] = f2bf(s[i + j]);
}

// ---------------------------------------------------------------------------
// LN stats: per (b,s) mean/rstd over c.  Coalesced reads along s.
// ---------------------------------------------------------------------------
__global__ __launch_bounds__(256) void ln_stats_kernel(const float* __restrict__ x,
                                                       float* __restrict__ muA,
                                                       float* __restrict__ rsA) {
    int bid = blockIdx.x;
    int b = bid >> 5, s0 = (bid & 31) * 32;
    int t = threadIdx.x, tc = t >> 5, ts = t & 31;
    const float* xp = x + (size_t)b * EMBED * S_LEN + s0 + ts;
    float sm = 0.f, sq = 0.f;
    for (int i = 0; i < 64; ++i) {
        float v = xp[(size_t)(tc * 64 + i) * S_LEN];
        sm += v; sq += v * v;
    }
    __shared__ float Sm[8][32], Sq[8][32];
    Sm[tc][ts] = sm; Sq[tc][ts] = sq;
    __syncthreads();
    if (t < 32) {
        float m = 0.f, q = 0.f;
#pragma unroll
        for (int j = 0; j < 8; ++j) { m += Sm[j][t]; q += Sq[j][t]; }
        float mu = m * (1.0f / EMBED);
        float var = q * (1.0f / EMBED) - mu * mu;
        muA[b * S_LEN + s0 + t] = mu;
        rsA[b * S_LEN + s0 + t] = rsqrtf(var + 1e-5f);
    }
}

// ---------------------------------------------------------------------------
// LN transpose+normalize: x[b,c,s] f32 -> xn[b,s,c] bf16 (32x32 LDS tile)
// ---------------------------------------------------------------------------
__global__ __launch_bounds__(256) void ln_tr_kernel(const float* __restrict__ x,
                                                    const float* __restrict__ muA,
                                                    const float* __restrict__ rsA,
                                                    const float* __restrict__ gamma,
                                                    const float* __restrict__ beta,
                                                    bf16_t* __restrict__ xn) {
    __shared__ float T[32][33];
    int tx = threadIdx.x & 31, ty = threadIdx.x >> 5;
    int b = blockIdx.z, c0 = blockIdx.y * 32, s0 = blockIdx.x * 32;
#pragma unroll
    for (int i = 0; i < 4; ++i) {
        int cr = ty + i * 8;
        T[cr][tx] = x[((size_t)b * EMBED + c0 + cr) * S_LEN + s0 + tx];
    }
    __syncthreads();
    float g = gamma[c0 + tx], be = beta[c0 + tx];
#pragma unroll
    for (int i = 0; i < 4; ++i) {
        int sr = ty + i * 8;
        float mu = muA[b * S_LEN + s0 + sr];
        float rs = rsA[b * S_LEN + s0 + sr];
        xn[((size_t)b * S_LEN + s0 + sr) * EMBED + c0 + tx] =
            f2bf((T[tx][sr] - mu) * rs * g + be);
    }
}

// ---------------------------------------------------------------------------
// Act-stationary GEMM  Y[m, col] = sum_k X[m,k]*W[col,k] + bias[col]
// (QK projection: W = packed [1024][512], bias split b0/b1 at col 512)
// block: 128 rows x 64 cols; W-tile (64x512, pad 520) in LDS; A streamed with
// explicit next-step register prefetch.
// ---------------------------------------------------------------------------
__global__ __launch_bounds__(256) void gemm_kernel(const bf16_t* __restrict__ X,
                                                   const bf16_t* __restrict__ W,
                                                   const float* __restrict__ b0,
                                                   const float* __restrict__ b1,
                                                   bf16_t* __restrict__ Y, int ldY) {
    __shared__ __align__(16) bf16_t Wl[64 * 520];
    int t = threadIdx.x;
    int col0 = blockIdx.y * 64, row0 = blockIdx.x * 128;
    {
        int row = t >> 2, seg = (t & 3) * 128;
        const bf16_t* src = W + (size_t)(col0 + row) * EMBED + seg;
        bf16_t* dst = &Wl[row * 520 + seg];
#pragma unroll
        for (int i = 0; i < 16; ++i)
            *(bf16x8*)(dst + i * 8) = *(const bf16x8*)(src + i * 8);
    }
    __syncthreads();
    int lane = t & 63, w = t >> 6, g = lane >> 4, n16 = lane & 15;
    int rw0 = row0 + w * 32;
    const bf16_t* xr0 = X + (size_t)(rw0 + n16) * EMBED + g * 8;
    const bf16_t* xr1 = xr0 + (size_t)16 * EMBED;
    floatx4 acc[2][4] = {};
    bf16x8 a0 = *(const bf16x8*)(xr0);
    bf16x8 a1 = *(const bf16x8*)(xr1);
#pragma unroll
    for (int ks = 0; ks < 16; ++ks) {
        bf16x8 na0, na1;
        if (ks < 15) {
            na0 = *(const bf16x8*)(xr0 + (ks + 1) * 32);
            na1 = *(const bf16x8*)(xr1 + (ks + 1) * 32);
        }
        int k32 = ks * 32;
#pragma unroll
        for (int nt = 0; nt < 4; ++nt) {
            bf16x8 bfr = *(const bf16x8*)(&Wl[(nt * 16 + n16) * 520 + k32 + g * 8]);
            acc[0][nt] = MFMA16(a0, bfr, acc[0][nt]);
            acc[1][nt] = MFMA16(a1, bfr, acc[1][nt]);
        }
        a0 = na0; a1 = na1;
    }
#pragma unroll
    for (int ar = 0; ar < 2; ++ar)
#pragma unroll
        for (int nt = 0; nt < 4; ++nt) {
            int col = col0 + nt * 16 + n16;
            float bv = (col < 512) ? b0[col] : b1[col - 512];
#pragma unroll
            for (int r = 0; r < 4; ++r) {
                int row = rw0 + ar * 16 + g * 4 + r;
                Y[(size_t)row * ldY + col] = f2bf(acc[ar][nt][r] + bv);
            }
        }
}

// ---------------------------------------------------------------------------
// Weight-stationary GEMM, V-projection transposed output (padded row LDV):
// vt[b][m][n] = sum_k Wv[m][k] * xn[b][n][k] + bv[m]   (m=channel, n=token)
// ---------------------------------------------------------------------------
__global__ __launch_bounds__(256) void wsgemm_vt_kernel(const bf16_t* __restrict__ Wb,
                                                        const bf16_t* __restrict__ act,
                                                        const float* __restrict__ bias,
                                                        bf16_t* __restrict__ vtb) {
    __shared__ __align__(16) bf16_t Al[64 * 520];
    int b = blockIdx.z, n0 = blockIdx.x * 64, m0 = blockIdx.y * 128;
    int t = threadIdx.x;
    {
        int row = t >> 2, seg = (t & 3) * 128;
        const bf16_t* src = act + ((size_t)b * S_LEN + n0 + row) * EMBED + seg;
        bf16_t* dst = &Al[row * 520 + seg];
#pragma unroll
        for (int i = 0; i < 16; ++i)
            *(bf16x8*)(dst + i * 8) = *(const bf16x8*)(src + i * 8);
    }
    __syncthreads();
    int lane = t & 63, w = t >> 6, g = lane >> 4, n16 = lane & 15;
    int mw = m0 + w * 32;
    const bf16_t* wr0 = Wb + (size_t)(mw + n16) * EMBED + g * 8;
    const bf16_t* wr1 = wr0 + (size_t)16 * EMBED;
    floatx4 acc[2][4] = {};
    bf16x8 a0 = *(const bf16x8*)(wr0);
    bf16x8 a1 = *(const bf16x8*)(wr1);
#pragma unroll
    for (int ks = 0; ks < 16; ++ks) {
        bf16x8 na0, na1;
        if (ks < 15) {
            na0 = *(const bf16x8*)(wr0 + (ks + 1) * 32);
            na1 = *(const bf16x8*)(wr1 + (ks + 1) * 32);
        }
        int k32 = ks * 32;
#pragma unroll
        for (int nt = 0; nt < 4; ++nt) {
            bf16x8 bfr = *(const bf16x8*)(&Al[(nt * 16 + n16) * 520 + k32 + g * 8]);
            acc[0][nt] = MFMA16(a0, bfr, acc[0][nt]);
            acc[1][nt] = MFMA16(a1, bfr, acc[1][nt]);
        }
        a0 = na0; a1 = na1;
    }
#pragma unroll
    for (int ar = 0; ar < 2; ++ar)
#pragma unroll
        for (int r = 0; r < 4; ++r) {
            int row = mw + ar * 16 + g * 4 + r;
            float bv = bias[row];
#pragma unroll
            for (int nt = 0; nt < 4; ++nt) {
                int col = n0 + nt * 16 + n16;
                vtb[((size_t)b * EMBED + row) * LDV + col] = f2bf(acc[ar][nt][r] + bv);
            }
        }
}

// ---------------------------------------------------------------------------
// Weight-stationary GEMM, O-projection + bias + residual, NCHW f32 output:
// out[b][m][n] = sum_k Wo[m][k] * ab[b][n][k] + bo[m] + x[b][m][n]
// ---------------------------------------------------------------------------
__global__ __launch_bounds__(256) void wsgemm_out_kernel(const bf16_t* __restrict__ Wb,
                                                         const bf16_t* __restrict__ act,
                                                         const float* __restrict__ bias,
                                                         const float* __restrict__ xres,
                                                         float* __restrict__ out) {
    __shared__ __align__(16) bf16_t Al[64 * 520];
    int b = blockIdx.z, n0 = blockIdx.x * 64, m0 = blockIdx.y * 128;
    int t = threadIdx.x;
    {
        int row = t >> 2, seg = (t & 3) * 128;
        const bf16_t* src = act + ((size_t)b * S_LEN + n0 + row) * EMBED + seg;
        bf16_t* dst = &Al[row * 520 + seg];
#pragma unroll
        for (int i = 0; i < 16; ++i)
            *(bf16x8*)(dst + i * 8) = *(const bf16x8*)(src + i * 8);
    }
    __syncthreads();
    int lane = t & 63, w = t >> 6, g = lane >> 4, n16 = lane & 15;
    int mw = m0 + w * 32;
    const bf16_t* wr0 = Wb + (size_t)(mw + n16) * EMBED + g * 8;
    const bf16_t* wr1 = wr0 + (size_t)16 * EMBED;
    floatx4 acc[2][4] = {};
    bf16x8 a0 = *(const bf16x8*)(wr0);
    bf16x8 a1 = *(const bf16x8*)(wr1);
#pragma unroll
    for (int ks = 0; ks < 16; ++ks) {
        bf16x8 na0, na1;
        if (ks < 15) {
            na0 = *(const bf16x8*)(wr0 + (ks + 1) * 32);
            na1 = *(const bf16x8*)(wr1 + (ks + 1) * 32);
        }
        int k32 = ks * 32;
#pragma unroll
        for (int nt = 0; nt < 4; ++nt) {
            bf16x8 bfr = *(const bf16x8*)(&Al[(nt * 16 + n16) * 520 + k32 + g * 8]);
            acc[0][nt] = MFMA16(a0, bfr, acc[0][nt]);
            acc[1][nt] = MFMA16(a1, bfr, acc[1][nt]);
        }
        a0 = na0; a1 = na1;
    }
#pragma unroll
    for (int ar = 0; ar < 2; ++ar)
#pragma unroll
        for (int r = 0; r < 4; ++r) {
            int row = mw + ar * 16 + g * 4 + r;
            float bv = bias[row];
#pragma unroll
            for (int nt = 0; nt < 4; ++nt) {
                int col = n0 + nt * 16 + n16;
                size_t oi = ((size_t)b * EMBED + row) * S_LEN + col;
                out[oi] = acc[ar][nt][r] + bv + xres[oi];
            }
        }
}

// ---------------------------------------------------------------------------
// Flash attention, transposed-softmax, barrier-free, register-double-buffered.
// grid: bid&63=(b,h) [XCD L2 locality], bid>>6=qt; 4 waves x 16 q.
// K[i+1]/V[i+1] fragments are loaded into registers BEFORE the softmax of
// tile i, hiding L2 latency behind compute.
// ---------------------------------------------------------------------------
__global__ __launch_bounds__(256) void attn_kernel(const bf16_t* __restrict__ qk,
                                                   const bf16_t* __restrict__ vt,
                                                   bf16_t* __restrict__ o) {
    __shared__ __align__(16) unsigned int Pl[4][16 * 36];  // per-wave P^T [16 q][72 bf16]
    int bid = blockIdx.x;
    int bh = bid & 63, qt = bid >> 6;
    int b = bh >> 3, h = bh & 7;
    int t = threadIdx.x, w = t >> 6, lane = t & 63, g = lane >> 4, n16 = lane & 15;
    size_t baseQK = (size_t)b * S_LEN * LDK;
    size_t baseV  = ((size_t)b * EMBED + h * HD) * LDV;
    int q_glob = qt * 64 + w * 16 + n16;

    const bf16_t* qp = qk + baseQK + (size_t)q_glob * LDK + h * HD + g * 8;
    bf16x8 qf0 = *(const bf16x8*)(qp);
    bf16x8 qf1 = *(const bf16x8*)(qp + 32);
#pragma unroll
    for (int j = 0; j < 8; ++j) {                          // pre-scale by 1/sqrt(64)
        qf0[j] = f2bf(bf2f(qf0[j]) * 0.125f);
        qf1[j] = f2bf(bf2f(qf1[j]) * 0.125f);
    }
    const bf16_t* kbase = qk + baseQK + 512 + h * HD;
    const bf16_t* vbase = vt + baseV;

    float m_i = -1e30f, l_i = 0.f;
    floatx4 oacc[4] = {};
    unsigned int* PLw = &Pl[w][0];

    // current-tile K/V fragments
    bf16x8 kc[8], vc[8];
#pragma unroll
    for (int kb = 0; kb < 4; ++kb) {
        const bf16_t* kp = kbase + (size_t)(kb * 16 + n16) * LDK + g * 8;
        kc[2 * kb]     = *(const bf16x8*)(kp);
        kc[2 * kb + 1] = *(const bf16x8*)(kp + 32);
        const bf16_t* vp = vbase + (size_t)(kb * 16 + n16) * LDV + g * 8;
        vc[2 * kb]     = *(const bf16x8*)(vp);
        vc[2 * kb + 1] = *(const bf16x8*)(vp + 32);
    }

    for (int kt = 0; kt < S_LEN; kt += 64) {
        // ---- prefetch next tile's K/V into registers (1 iter ahead) ----
        bf16x8 kn[8], vn[8];
        if (kt + 64 < S_LEN) {
            int ktn = kt + 64;
#pragma unroll
            for (int kb = 0; kb < 4; ++kb) {
                const bf16_t* kp = kbase + (size_t)(ktn + kb * 16 + n16) * LDK + g * 8;
                kn[2 * kb]     = *(const bf16x8*)(kp);
                kn[2 * kb + 1] = *(const bf16x8*)(kp + 32);
                const bf16_t* vp = vbase + (size_t)(kb * 16 + n16) * LDV + ktn + g * 8;
                vn[2 * kb]     = *(const bf16x8*)(vp);
                vn[2 * kb + 1] = *(const bf16x8*)(vp + 32);
            }
        }
        // ---- S^T: 64 keys (rows) x 16 q (cols) ----
        floatx4 s[4] = {};
#pragma unroll
        for (int kb = 0; kb < 4; ++kb) {
            s[kb] = MFMA16(kc[2 * kb], qf0, s[kb]);
            s[kb] = MFMA16(kc[2 * kb + 1], qf1, s[kb]);
        }
        // ---- softmax: lane owns q=n16, 16 key-scores in regs ----
        float mx = -1e30f;
#pragma unroll
        for (int kb = 0; kb < 4; ++kb)
#pragma unroll
            for (int r = 0; r < 4; ++r) mx = fmaxf(mx, s[kb][r]);
        mx = fmaxf(mx, __shfl_xor(mx, 16));
        mx = fmaxf(mx, __shfl_xor(mx, 32));
        float mn = fmaxf(m_i, mx);
        float rs = 0.f;
#pragma unroll
        for (int kb = 0; kb < 4; ++kb)
#pragma unroll
            for (int r = 0; r < 4; ++r) {
                s[kb][r] = __expf(s[kb][r] - mn);
                rs += s[kb][r];
            }
        rs += __shfl_xor(rs, 16);
        rs += __shfl_xor(rs, 32);
        float al = __expf(m_i - mn);
        l_i = l_i * al + rs;
        m_i = mn;
#pragma unroll
        for (int dt = 0; dt < 4; ++dt)
#pragma unroll
            for (int r = 0; r < 4; ++r) oacc[dt][r] *= al;

        // ---- P^T -> per-wave LDS (bf16 [q][72]) -> B-fragments ----
#pragma unroll
        for (int kb = 0; kb < 4; ++kb) {
            uint2 pr;
            pr.x = pack2(s[kb][0], s[kb][1]);
            pr.y = pack2(s[kb][2], s[kb][3]);
            *(uint2*)&PLw[n16 * 36 + kb * 8 + g * 2] = pr;
        }
        uint4 u0 = *(const uint4*)&PLw[n16 * 36 + g * 4];
        uint4 u1 = *(const uint4*)&PLw[n16 * 36 + 16 + g * 4];
        bf16x8 pf0 = __builtin_bit_cast(bf16x8, u0);
        bf16x8 pf1 = __builtin_bit_cast(bf16x8, u1);

        // ---- O^T += V^T P^T ----
#pragma unroll
        for (int dt = 0; dt < 4; ++dt) {
            oacc[dt] = MFMA16(vc[2 * dt], pf0, oacc[dt]);
            oacc[dt] = MFMA16(vc[2 * dt + 1], pf1, oacc[dt]);
        }
        // ---- rotate double buffers ----
#pragma unroll
        for (int i = 0; i < 8; ++i) { kc[i] = kn[i]; vc[i] = vn[i]; }
    }
    // ---- epilogue: lane q=n16, d=dt*16+g*4+r -> ab[b*1024+q][h*64+d] ----
    float rl = 1.0f / l_i;
    size_t orow = ((size_t)b * S_LEN + q_glob) * EMBED + h * HD;
#pragma unroll
    for (int dt = 0; dt < 4; ++dt) {
        uint2 pr;
        pr.x = pack2(oacc[dt][0] * rl, oacc[dt][1] * rl);
        pr.y = pack2(oacc[dt][2] * rl, oacc[dt][3] * rl);
        *(uint2*)(o + orow + dt * 16 + g * 4) = pr;
    }
}

extern "C" void kernel_launch(void* const* d_in, const int* in_sizes, int n_in,
                              void* d_out, int out_size, void* d_ws, size_t ws_size,
                              hipStream_t stream) {
    const float* x     = (const float*)d_in[0];
    const float* Wq    = (const float*)d_in[1];
    const float* bq    = (const float*)d_in[2];
    const float* Wk    = (const float*)d_in[3];
    const float* bk    = (const float*)d_in[4];
    const float* Wv    = (const float*)d_in[5];
    const float* bv    = (const float*)d_in[6];
    const float* Wo    = (const float*)d_in[7];
    const float* bo    = (const float*)d_in[8];
    const float* gamma = (const float*)d_in[9];
    const float* beta  = (const float*)d_in[10];
    float* out = (float*)d_out;

    char* ws = (char*)d_ws;                        // ~27.9 MB used
    bf16_t* xn   = (bf16_t*)ws;                    // [0,8M); reused as attn-out
    bf16_t* qkb  = (bf16_t*)(ws + 8388608);        // packed QK [8192][1056] (17.3 MB)
    bf16_t* wqk  = (bf16_t*)(ws + 25690112);       // 1 MB packed [1024][512]
    bf16_t* wv   = (bf16_t*)(ws + 26738688);       // 512 KB
    bf16_t* wo   = (bf16_t*)(ws + 27262976);       // 512 KB
    float*  muA  = (float*)(ws + 27787264);        // 32 KB
    float*  rsA  = (float*)(ws + 27820032);        // 32 KB
    bf16_t* ab   = xn;

    // vt lives in d_out (8.9 MB used of 16.8): dead before wsgemm_out writes out
    bf16_t* vtb = (bf16_t*)d_out;

    cvt4_kernel<<<dim3(128, 4), 256, 0, stream>>>(Wq, Wk, Wv, Wo,
                                                  wqk, wqk + 262144, wv, wo);
    ln_stats_kernel<<<dim3(256), 256, 0, stream>>>(x, muA, rsA);
    ln_tr_kernel<<<dim3(32, 16, 8), 256, 0, stream>>>(x, muA, rsA, gamma, beta, xn);
    gemm_kernel<<<dim3(64, 16), 256, 0, stream>>>(xn, wqk, bq, bk, qkb, LDK);
    wsgemm_vt_kernel<<<dim3(16, 4, 8), 256, 0, stream>>>(wv, xn, bv, vtb);
    attn_kernel<<<dim3(1024), 256, 0, stream>>>(qkb, vtb, ab);
    wsgemm_out_kernel<<<dim3(16, 4, 8), 256, 0, stream>>>(wo, ab, bo, x, out);
}

// Round 6
// 231.602 us; speedup vs baseline: 1.6607x; 1.1229x over previous
//
#include <hip/hip_runtime.h>
#include <hip/hip_bf16.h>

typedef __bf16 bf16_t;
typedef __bf16 bf16x8 __attribute__((ext_vector_type(8)));
typedef float floatx4 __attribute__((ext_vector_type(4)));

#define EMBED 512
#define S_LEN 1024
#define NH 8
#define HD 64
#define LDK 1056   // padded row stride of packed QK buffer (breaks 2KB L2 camping)
#define LDV 1088   // padded row stride of V^T buffer

#define MFMA16(a, b, c) __builtin_amdgcn_mfma_f32_16x16x32_bf16(a, b, c, 0, 0, 0)

static __device__ __forceinline__ bf16_t f2bf(float f) {
    unsigned int x = __builtin_bit_cast(unsigned int, f);
    unsigned int lsb = (x >> 16) & 1u;
    x += 0x7fffu + lsb;                 // RNE
    unsigned short u = (unsigned short)(x >> 16);
    return __builtin_bit_cast(bf16_t, u);
}
static __device__ __forceinline__ float bf2f(bf16_t v) {
    unsigned short u = __builtin_bit_cast(unsigned short, v);
    unsigned int x = ((unsigned int)u) << 16;
    return __builtin_bit_cast(float, x);
}
// pack two f32 -> one u32 holding two bf16 (truncate)
static __device__ __forceinline__ unsigned int pack2(float lo, float hi) {
    return (__builtin_bit_cast(unsigned int, lo) >> 16) |
           (__builtin_bit_cast(unsigned int, hi) & 0xFFFF0000u);
}

// ---------------------------------------------------------------------------
// f32 -> bf16 conversion for the 4 weight matrices in one launch
// ---------------------------------------------------------------------------
__global__ __launch_bounds__(256) void cvt4_kernel(const float* __restrict__ s0,
                                                   const float* __restrict__ s1,
                                                   const float* __restrict__ s2,
                                                   const float* __restrict__ s3,
                                                   bf16_t* __restrict__ d0,
                                                   bf16_t* __restrict__ d1,
                                                   bf16_t* __restrict__ d2,
                                                   bf16_t* __restrict__ d3) {
    const float* s; bf16_t* d;
    switch (blockIdx.y) {
        case 0:  s = s0; d = d0; break;
        case 1:  s = s1; d = d1; break;
        case 2:  s = s2; d = d2; break;
        default: s = s3; d = d3; break;
    }
    int i = (blockIdx.x * 256 + threadIdx.x) * 8;
#pragma unroll
    for (int j = 0; j < 8; ++j) d[i + j] = f2bf(s[i + j]);
}

// ---------------------------------------------------------------------------
// LN stats: per (b,s) mean/rstd over c.  Coalesced reads along s.
// ---------------------------------------------------------------------------
__global__ __launch_bounds__(256) void ln_stats_kernel(const float* __restrict__ x,
                                                       float* __restrict__ muA,
                                                       float* __restrict__ rsA) {
    int bid = blockIdx.x;
    int b = bid >> 5, s0 = (bid & 31) * 32;
    int t = threadIdx.x, tc = t >> 5, ts = t & 31;
    const float* xp = x + (size_t)b * EMBED * S_LEN + s0 + ts;
    float sm = 0.f, sq = 0.f;
    for (int i = 0; i < 64; ++i) {
        float v = xp[(size_t)(tc * 64 + i) * S_LEN];
        sm += v; sq += v * v;
    }
    __shared__ float Sm[8][32], Sq[8][32];
    Sm[tc][ts] = sm; Sq[tc][ts] = sq;
    __syncthreads();
    if (t < 32) {
        float m = 0.f, q = 0.f;
#pragma unroll
        for (int j = 0; j < 8; ++j) { m += Sm[j][t]; q += Sq[j][t]; }
        float mu = m * (1.0f / EMBED);
        float var = q * (1.0f / EMBED) - mu * mu;
        muA[b * S_LEN + s0 + t] = mu;
        rsA[b * S_LEN + s0 + t] = rsqrtf(var + 1e-5f);
    }
}

// ---------------------------------------------------------------------------
// LN transpose+normalize: x[b,c,s] f32 -> xn[b,s,c] bf16 (32x32 LDS tile)
// ---------------------------------------------------------------------------
__global__ __launch_bounds__(256) void ln_tr_kernel(const float* __restrict__ x,
                                                    const float* __restrict__ muA,
                                                    const float* __restrict__ rsA,
                                                    const float* __restrict__ gamma,
                                                    const float* __restrict__ beta,
                                                    bf16_t* __restrict__ xn) {
    __shared__ float T[32][33];
    int tx = threadIdx.x & 31, ty = threadIdx.x >> 5;
    int b = blockIdx.z, c0 = blockIdx.y * 32, s0 = blockIdx.x * 32;
#pragma unroll
    for (int i = 0; i < 4; ++i) {
        int cr = ty + i * 8;
        T[cr][tx] = x[((size_t)b * EMBED + c0 + cr) * S_LEN + s0 + tx];
    }
    __syncthreads();
    float g = gamma[c0 + tx], be = beta[c0 + tx];
#pragma unroll
    for (int i = 0; i < 4; ++i) {
        int sr = ty + i * 8;
        float mu = muA[b * S_LEN + s0 + sr];
        float rs = rsA[b * S_LEN + s0 + sr];
        xn[((size_t)b * S_LEN + s0 + sr) * EMBED + c0 + tx] =
            f2bf((T[tx][sr] - mu) * rs * g + be);
    }
}

// ---------------------------------------------------------------------------
// Act-stationary GEMM  Y[m, col] = sum_k X[m,k]*W[col,k] + bias[col]
// (QK projection: W = packed [1024][512], bias split b0/b1 at col 512)
// k-chunked double-buffered LDS staging of W (2 x 64x64 chunks, stride 72);
// X rows streamed with chunk-ahead register prefetch.
// ---------------------------------------------------------------------------
__global__ __launch_bounds__(256) void gemm_kernel(const bf16_t* __restrict__ X,
                                                   const bf16_t* __restrict__ W,
                                                   const float* __restrict__ b0,
                                                   const float* __restrict__ b1,
                                                   bf16_t* __restrict__ Y, int ldY) {
    __shared__ __align__(16) bf16_t Wl[2][64 * 72];
    int t = threadIdx.x;
    int col0 = blockIdx.y * 64, row0 = blockIdx.x * 128;
    int scol = t >> 2, sseg = (t & 3) * 16;
    const bf16_t* wsrc = W + (size_t)(col0 + scol) * EMBED + sseg;
    {   // preload chunk 0
        bf16x8 r0 = *(const bf16x8*)(wsrc);
        bf16x8 r1 = *(const bf16x8*)(wsrc + 8);
        bf16_t* d = &Wl[0][scol * 72 + sseg];
        *(bf16x8*)d = r0; *(bf16x8*)(d + 8) = r1;
    }
    int lane = t & 63, w = t >> 6, g = lane >> 4, n16 = lane & 15;
    int rw0 = row0 + w * 32;
    const bf16_t* xr0 = X + (size_t)(rw0 + n16) * EMBED + g * 8;
    const bf16_t* xr1 = xr0 + (size_t)16 * EMBED;
    bf16x8 a00 = *(const bf16x8*)(xr0);
    bf16x8 a01 = *(const bf16x8*)(xr0 + 32);
    bf16x8 a10 = *(const bf16x8*)(xr1);
    bf16x8 a11 = *(const bf16x8*)(xr1 + 32);
    __syncthreads();
    floatx4 acc[2][4] = {};
#pragma unroll
    for (int kc = 0; kc < 8; ++kc) {
        bf16x8 p0, p1, na00, na01, na10, na11;
        if (kc < 7) {
            int ko = (kc + 1) * 64;
            p0 = *(const bf16x8*)(wsrc + ko);
            p1 = *(const bf16x8*)(wsrc + ko + 8);
            na00 = *(const bf16x8*)(xr0 + ko);
            na01 = *(const bf16x8*)(xr0 + ko + 32);
            na10 = *(const bf16x8*)(xr1 + ko);
            na11 = *(const bf16x8*)(xr1 + ko + 32);
        }
        const bf16_t* wl = &Wl[kc & 1][0];
#pragma unroll
        for (int kk = 0; kk < 2; ++kk) {
            bf16x8 s0 = (kk == 0) ? a00 : a01;
            bf16x8 s1 = (kk == 0) ? a10 : a11;
#pragma unroll
            for (int nt = 0; nt < 4; ++nt) {
                bf16x8 bfr = *(const bf16x8*)(&wl[(nt * 16 + n16) * 72 + kk * 32 + g * 8]);
                acc[0][nt] = MFMA16(s0, bfr, acc[0][nt]);
                acc[1][nt] = MFMA16(s1, bfr, acc[1][nt]);
            }
        }
        if (kc < 7) {
            bf16_t* d = &Wl[(kc + 1) & 1][scol * 72 + sseg];
            *(bf16x8*)d = p0; *(bf16x8*)(d + 8) = p1;
            a00 = na00; a01 = na01; a10 = na10; a11 = na11;
        }
        __syncthreads();
    }
#pragma unroll
    for (int ar = 0; ar < 2; ++ar)
#pragma unroll
        for (int nt = 0; nt < 4; ++nt) {
            int col = col0 + nt * 16 + n16;
            float bv = (col < 512) ? b0[col] : b1[col - 512];
#pragma unroll
            for (int r = 0; r < 4; ++r) {
                int row = rw0 + ar * 16 + g * 4 + r;
                Y[(size_t)row * ldY + col] = f2bf(acc[ar][nt][r] + bv);
            }
        }
}

// ---------------------------------------------------------------------------
// Weight-stationary GEMM, V-projection transposed output (padded row LDV):
// vt[b][m][n] = sum_k Wv[m][k] * xn[b][n][k] + bv[m]   (m=channel, n=token)
// k-chunked double-buffered LDS staging of act; W rows streamed w/ prefetch.
// ---------------------------------------------------------------------------
__global__ __launch_bounds__(256) void wsgemm_vt_kernel(const bf16_t* __restrict__ Wb,
                                                        const bf16_t* __restrict__ act,
                                                        const float* __restrict__ bias,
                                                        bf16_t* __restrict__ vtb) {
    __shared__ __align__(16) bf16_t Al[2][64 * 72];
    int b = blockIdx.z, n0 = blockIdx.x * 64, m0 = blockIdx.y * 128;
    int t = threadIdx.x;
    int srow = t >> 2, sseg = (t & 3) * 16;
    const bf16_t* asrc = act + ((size_t)b * S_LEN + n0 + srow) * EMBED + sseg;
    {
        bf16x8 r0 = *(const bf16x8*)(asrc);
        bf16x8 r1 = *(const bf16x8*)(asrc + 8);
        bf16_t* d = &Al[0][srow * 72 + sseg];
        *(bf16x8*)d = r0; *(bf16x8*)(d + 8) = r1;
    }
    int lane = t & 63, w = t >> 6, g = lane >> 4, n16 = lane & 15;
    int mw = m0 + w * 32;
    const bf16_t* wr0 = Wb + (size_t)(mw + n16) * EMBED + g * 8;
    const bf16_t* wr1 = wr0 + (size_t)16 * EMBED;
    bf16x8 a00 = *(const bf16x8*)(wr0);
    bf16x8 a01 = *(const bf16x8*)(wr0 + 32);
    bf16x8 a10 = *(const bf16x8*)(wr1);
    bf16x8 a11 = *(const bf16x8*)(wr1 + 32);
    __syncthreads();
    floatx4 acc[2][4] = {};
#pragma unroll
    for (int kc = 0; kc < 8; ++kc) {
        bf16x8 p0, p1, na00, na01, na10, na11;
        if (kc < 7) {
            int ko = (kc + 1) * 64;
            p0 = *(const bf16x8*)(asrc + ko);
            p1 = *(const bf16x8*)(asrc + ko + 8);
            na00 = *(const bf16x8*)(wr0 + ko);
            na01 = *(const bf16x8*)(wr0 + ko + 32);
            na10 = *(const bf16x8*)(wr1 + ko);
            na11 = *(const bf16x8*)(wr1 + ko + 32);
        }
        const bf16_t* al = &Al[kc & 1][0];
#pragma unroll
        for (int kk = 0; kk < 2; ++kk) {
            bf16x8 s0 = (kk == 0) ? a00 : a01;
            bf16x8 s1 = (kk == 0) ? a10 : a11;
#pragma unroll
            for (int nt = 0; nt < 4; ++nt) {
                bf16x8 bfr = *(const bf16x8*)(&al[(nt * 16 + n16) * 72 + kk * 32 + g * 8]);
                acc[0][nt] = MFMA16(s0, bfr, acc[0][nt]);
                acc[1][nt] = MFMA16(s1, bfr, acc[1][nt]);
            }
        }
        if (kc < 7) {
            bf16_t* d = &Al[(kc + 1) & 1][srow * 72 + sseg];
            *(bf16x8*)d = p0; *(bf16x8*)(d + 8) = p1;
            a00 = na00; a01 = na01; a10 = na10; a11 = na11;
        }
        __syncthreads();
    }
#pragma unroll
    for (int ar = 0; ar < 2; ++ar)
#pragma unroll
        for (int r = 0; r < 4; ++r) {
            int row = mw + ar * 16 + g * 4 + r;
            float bv = bias[row];
#pragma unroll
            for (int nt = 0; nt < 4; ++nt) {
                int col = n0 + nt * 16 + n16;
                vtb[((size_t)b * EMBED + row) * LDV + col] = f2bf(acc[ar][nt][r] + bv);
            }
        }
}

// ---------------------------------------------------------------------------
// Weight-stationary GEMM, O-projection + bias + residual, NCHW f32 output
// ---------------------------------------------------------------------------
__global__ __launch_bounds__(256) void wsgemm_out_kernel(const bf16_t* __restrict__ Wb,
                                                         const bf16_t* __restrict__ act,
                                                         const float* __restrict__ bias,
                                                         const float* __restrict__ xres,
                                                         float* __restrict__ out) {
    __shared__ __align__(16) bf16_t Al[2][64 * 72];
    int b = blockIdx.z, n0 = blockIdx.x * 64, m0 = blockIdx.y * 128;
    int t = threadIdx.x;
    int srow = t >> 2, sseg = (t & 3) * 16;
    const bf16_t* asrc = act + ((size_t)b * S_LEN + n0 + srow) * EMBED + sseg;
    {
        bf16x8 r0 = *(const bf16x8*)(asrc);
        bf16x8 r1 = *(const bf16x8*)(asrc + 8);
        bf16_t* d = &Al[0][srow * 72 + sseg];
        *(bf16x8*)d = r0; *(bf16x8*)(d + 8) = r1;
    }
    int lane = t & 63, w = t >> 6, g = lane >> 4, n16 = lane & 15;
    int mw = m0 + w * 32;
    const bf16_t* wr0 = Wb + (size_t)(mw + n16) * EMBED + g * 8;
    const bf16_t* wr1 = wr0 + (size_t)16 * EMBED;
    bf16x8 a00 = *(const bf16x8*)(wr0);
    bf16x8 a01 = *(const bf16x8*)(wr0 + 32);
    bf16x8 a10 = *(const bf16x8*)(wr1);
    bf16x8 a11 = *(const bf16x8*)(wr1 + 32);
    __syncthreads();
    floatx4 acc[2][4] = {};
#pragma unroll
    for (int kc = 0; kc < 8; ++kc) {
        bf16x8 p0, p1, na00, na01, na10, na11;
        if (kc < 7) {
            int ko = (kc + 1) * 64;
            p0 = *(const bf16x8*)(asrc + ko);
            p1 = *(const bf16x8*)(asrc + ko + 8);
            na00 = *(const bf16x8*)(wr0 + ko);
            na01 = *(const bf16x8*)(wr0 + ko + 32);
            na10 = *(const bf16x8*)(wr1 + ko);
            na11 = *(const bf16x8*)(wr1 + ko + 32);
        }
        const bf16_t* al = &Al[kc & 1][0];
#pragma unroll
        for (int kk = 0; kk < 2; ++kk) {
            bf16x8 s0 = (kk == 0) ? a00 : a01;
            bf16x8 s1 = (kk == 0) ? a10 : a11;
#pragma unroll
            for (int nt = 0; nt < 4; ++nt) {
                bf16x8 bfr = *(const bf16x8*)(&al[(nt * 16 + n16) * 72 + kk * 32 + g * 8]);
                acc[0][nt] = MFMA16(s0, bfr, acc[0][nt]);
                acc[1][nt] = MFMA16(s1, bfr, acc[1][nt]);
            }
        }
        if (kc < 7) {
            bf16_t* d = &Al[(kc + 1) & 1][srow * 72 + sseg];
            *(bf16x8*)d = p0; *(bf16x8*)(d + 8) = p1;
            a00 = na00; a01 = na01; a10 = na10; a11 = na11;
        }
        __syncthreads();
    }
#pragma unroll
    for (int ar = 0; ar < 2; ++ar)
#pragma unroll
        for (int r = 0; r < 4; ++r) {
            int row = mw + ar * 16 + g * 4 + r;
            float bv = bias[row];
#pragma unroll
            for (int nt = 0; nt < 4; ++nt) {
                int col = n0 + nt * 16 + n16;
                size_t oi = ((size_t)b * EMBED + row) * S_LEN + col;
                out[oi] = acc[ar][nt][r] + bv + xres[oi];
            }
        }
}

// ---------------------------------------------------------------------------
// Flash attention, fixed-offset softmax (no running max), barrier-free,
// register-double-buffered K/V.  Scores accumulate onto C-init=-12;
// p = exp(min(s,40)) — uniform scale exp(m-12) cancels in O/l.  No cross-lane
// ops in the hot loop; l reduced once after the loop.
// ---------------------------------------------------------------------------
__global__ __launch_bounds__(256) void attn_kernel(const bf16_t* __restrict__ qk,
                                                   const bf16_t* __restrict__ vt,
                                                   bf16_t* __restrict__ o) {
    __shared__ __align__(16) unsigned int Pl[4][16 * 36];  // per-wave P^T [16 q][72 bf16]
    int bid = blockIdx.x;
    int bh = bid & 63, qt = bid >> 6;
    int b = bh >> 3, h = bh & 7;
    int t = threadIdx.x, w = t >> 6, lane = t & 63, g = lane >> 4, n16 = lane & 15;
    size_t baseQK = (size_t)b * S_LEN * LDK;
    size_t baseV  = ((size_t)b * EMBED + h * HD) * LDV;
    int q_glob = qt * 64 + w * 16 + n16;

    const bf16_t* qp = qk + baseQK + (size_t)q_glob * LDK + h * HD + g * 8;
    bf16x8 qf0 = *(const bf16x8*)(qp);
    bf16x8 qf1 = *(const bf16x8*)(qp + 32);
#pragma unroll
    for (int j = 0; j < 8; ++j) {                          // pre-scale by 1/sqrt(64)
        qf0[j] = f2bf(bf2f(qf0[j]) * 0.125f);
        qf1[j] = f2bf(bf2f(qf1[j]) * 0.125f);
    }
    const bf16_t* kbase = qk + baseQK + 512 + h * HD;
    const bf16_t* vbase = vt + baseV;

    float ls[4] = {0.f, 0.f, 0.f, 0.f};
    floatx4 oacc[4] = {};
    unsigned int* PLw = &Pl[w][0];

    bf16x8 kc[8], vc[8];
#pragma unroll
    for (int kb = 0; kb < 4; ++kb) {
        const bf16_t* kp = kbase + (size_t)(kb * 16 + n16) * LDK + g * 8;
        kc[2 * kb]     = *(const bf16x8*)(kp);
        kc[2 * kb + 1] = *(const bf16x8*)(kp + 32);
        const bf16_t* vp = vbase + (size_t)(kb * 16 + n16) * LDV + g * 8;
        vc[2 * kb]     = *(const bf16x8*)(vp);
        vc[2 * kb + 1] = *(const bf16x8*)(vp + 32);
    }

    for (int kt = 0; kt < S_LEN; kt += 64) {
        // ---- prefetch next tile's K/V (1 iter ahead) ----
        bf16x8 kn[8], vn[8];
        if (kt + 64 < S_LEN) {
            int ktn = kt + 64;
#pragma unroll
            for (int kb = 0; kb < 4; ++kb) {
                const bf16_t* kp = kbase + (size_t)(ktn + kb * 16 + n16) * LDK + g * 8;
                kn[2 * kb]     = *(const bf16x8*)(kp);
                kn[2 * kb + 1] = *(const bf16x8*)(kp + 32);
                const bf16_t* vp = vbase + (size_t)(kb * 16 + n16) * LDV + ktn + g * 8;
                vn[2 * kb]     = *(const bf16x8*)(vp);
                vn[2 * kb + 1] = *(const bf16x8*)(vp + 32);
            }
        }
        // ---- S^T = K Q^T - 12 : 64 keys (rows) x 16 q (cols) ----
        floatx4 s[4];
#pragma unroll
        for (int kb = 0; kb < 4; ++kb) {
            s[kb] = floatx4{-12.f, -12.f, -12.f, -12.f};
            s[kb] = MFMA16(kc[2 * kb], qf0, s[kb]);
            s[kb] = MFMA16(kc[2 * kb + 1], qf1, s[kb]);
        }
        // ---- p = exp(s), per-lane l partials; no cross-lane ops ----
#pragma unroll
        for (int kb = 0; kb < 4; ++kb) {
#pragma unroll
            for (int r = 0; r < 4; ++r) {
                float e = __expf(fminf(s[kb][r], 40.f));
                s[kb][r] = e;
                ls[kb] += e;
            }
        }
        // ---- P^T -> per-wave LDS (bf16 [q][72]) -> B-fragments ----
#pragma unroll
        for (int kb = 0; kb < 4; ++kb) {
            uint2 pr;
            pr.x = pack2(s[kb][0], s[kb][1]);
            pr.y = pack2(s[kb][2], s[kb][3]);
            *(uint2*)&PLw[n16 * 36 + kb * 8 + g * 2] = pr;
        }
        uint4 u0 = *(const uint4*)&PLw[n16 * 36 + g * 4];
        uint4 u1 = *(const uint4*)&PLw[n16 * 36 + 16 + g * 4];
        bf16x8 pf0 = __builtin_bit_cast(bf16x8, u0);
        bf16x8 pf1 = __builtin_bit_cast(bf16x8, u1);

        // ---- O^T += V^T P^T ----
#pragma unroll
        for (int dt = 0; dt < 4; ++dt) {
            oacc[dt] = MFMA16(vc[2 * dt], pf0, oacc[dt]);
            oacc[dt] = MFMA16(vc[2 * dt + 1], pf1, oacc[dt]);
        }
#pragma unroll
        for (int i = 0; i < 8; ++i) { kc[i] = kn[i]; vc[i] = vn[i]; }
    }
    // ---- l reduction (once) + epilogue ----
    float l = (ls[0] + ls[1]) + (ls[2] + ls[3]);
    l += __shfl_xor(l, 16);
    l += __shfl_xor(l, 32);
    float rl = 1.0f / l;
    size_t orow = ((size_t)b * S_LEN + q_glob) * EMBED + h * HD;
#pragma unroll
    for (int dt = 0; dt < 4; ++dt) {
        uint2 pr;
        pr.x = pack2(oacc[dt][0] * rl, oacc[dt][1] * rl);
        pr.y = pack2(oacc[dt][2] * rl, oacc[dt][3] * rl);
        *(uint2*)(o + orow + dt * 16 + g * 4) = pr;
    }
}

extern "C" void kernel_launch(void* const* d_in, const int* in_sizes, int n_in,
                              void* d_out, int out_size, void* d_ws, size_t ws_size,
                              hipStream_t stream) {
    const float* x     = (const float*)d_in[0];
    const float* Wq    = (const float*)d_in[1];
    const float* bq    = (const float*)d_in[2];
    const float* Wk    = (const float*)d_in[3];
    const float* bk    = (const float*)d_in[4];
    const float* Wv    = (const float*)d_in[5];
    const float* bv    = (const float*)d_in[6];
    const float* Wo    = (const float*)d_in[7];
    const float* bo    = (const float*)d_in[8];
    const float* gamma = (const float*)d_in[9];
    const float* beta  = (const float*)d_in[10];
    float* out = (float*)d_out;

    char* ws = (char*)d_ws;                        // ~27.9 MB used
    bf16_t* xn   = (bf16_t*)ws;                    // [0,8M); reused as attn-out
    bf16_t* qkb  = (bf16_t*)(ws + 8388608);        // packed QK [8192][1056] (17.3 MB)
    bf16_t* wqk  = (bf16_t*)(ws + 25690112);       // 1 MB packed [1024][512]
    bf16_t* wv   = (bf16_t*)(ws + 26738688);       // 512 KB
    bf16_t* wo   = (bf16_t*)(ws + 27262976);       // 512 KB
    float*  muA  = (float*)(ws + 27787264);        // 32 KB
    float*  rsA  = (float*)(ws + 27820032);        // 32 KB
    bf16_t* ab   = xn;

    // vt lives in d_out (8.9 MB used of 16.8): dead before wsgemm_out writes out
    bf16_t* vtb = (bf16_t*)d_out;

    cvt4_kernel<<<dim3(128, 4), 256, 0, stream>>>(Wq, Wk, Wv, Wo,
                                                  wqk, wqk + 262144, wv, wo);
    ln_stats_kernel<<<dim3(256), 256, 0, stream>>>(x, muA, rsA);
    ln_tr_kernel<<<dim3(32, 16, 8), 256, 0, stream>>>(x, muA, rsA, gamma, beta, xn);
    gemm_kernel<<<dim3(64, 16), 256, 0, stream>>>(xn, wqk, bq, bk, qkb, LDK);
    wsgemm_vt_kernel<<<dim3(16, 4, 8), 256, 0, stream>>>(wv, xn, bv, vtb);
    attn_kernel<<<dim3(1024), 256, 0, stream>>>(qkb, vtb, ab);
    wsgemm_out_kernel<<<dim3(16, 4, 8), 256, 0, stream>>>(wo, ab, bo, x, out);
}

// Round 7
// 174.380 us; speedup vs baseline: 2.2056x; 1.3281x over previous
//
#include <hip/hip_runtime.h>
#include <hip/hip_bf16.h>

typedef __bf16 bf16_t;
typedef __bf16 bf16x8 __attribute__((ext_vector_type(8)));
typedef float floatx4 __attribute__((ext_vector_type(4)));

#define EMBED 512
#define S_LEN 1024
#define NH 8
#define HD 64
#define LDK 1056   // padded row stride of packed QK buffer
#define LDV 1088   // padded row stride of V^T buffer

#define MFMA16(a, b, c) __builtin_amdgcn_mfma_f32_16x16x32_bf16(a, b, c, 0, 0, 0)

static __device__ __forceinline__ bf16_t f2bf(float f) {
    unsigned int x = __builtin_bit_cast(unsigned int, f);
    unsigned int lsb = (x >> 16) & 1u;
    x += 0x7fffu + lsb;                 // RNE
    unsigned short u = (unsigned short)(x >> 16);
    return __builtin_bit_cast(bf16_t, u);
}
static __device__ __forceinline__ float bf2f(bf16_t v) {
    unsigned short u = __builtin_bit_cast(unsigned short, v);
    unsigned int x = ((unsigned int)u) << 16;
    return __builtin_bit_cast(float, x);
}
// pack two f32 -> one u32 holding two bf16 (truncate)
static __device__ __forceinline__ unsigned int pack2(float lo, float hi) {
    return (__builtin_bit_cast(unsigned int, lo) >> 16) |
           (__builtin_bit_cast(unsigned int, hi) & 0xFFFF0000u);
}

// ---------------------------------------------------------------------------
// f32 -> bf16 conversion for the 4 weight matrices in one launch
// ---------------------------------------------------------------------------
__global__ __launch_bounds__(256) void cvt4_kernel(const float* __restrict__ s0,
                                                   const float* __restrict__ s1,
                                                   const float* __restrict__ s2,
                                                   const float* __restrict__ s3,
                                                   bf16_t* __restrict__ d0,
                                                   bf16_t* __restrict__ d1,
                                                   bf16_t* __restrict__ d2,
                                                   bf16_t* __restrict__ d3) {
    const float* s; bf16_t* d;
    switch (blockIdx.y) {
        case 0:  s = s0; d = d0; break;
        case 1:  s = s1; d = d1; break;
        case 2:  s = s2; d = d2; break;
        default: s = s3; d = d3; break;
    }
    int i = (blockIdx.x * 256 + threadIdx.x) * 8;
#pragma unroll
    for (int j = 0; j < 8; ++j) d[i + j] = f2bf(s[i + j]);
}

// ---------------------------------------------------------------------------
// LN stats: per (b,s) mean/rstd over c.  Coalesced reads along s.
// ---------------------------------------------------------------------------
__global__ __launch_bounds__(256) void ln_stats_kernel(const float* __restrict__ x,
                                                       float* __restrict__ muA,
                                                       float* __restrict__ rsA) {
    int bid = blockIdx.x;
    int b = bid >> 5, s0 = (bid & 31) * 32;
    int t = threadIdx.x, tc = t >> 5, ts = t & 31;
    const float* xp = x + (size_t)b * EMBED * S_LEN + s0 + ts;
    float sm = 0.f, sq = 0.f;
    for (int i = 0; i < 64; ++i) {
        float v = xp[(size_t)(tc * 64 + i) * S_LEN];
        sm += v; sq += v * v;
    }
    __shared__ float Sm[8][32], Sq[8][32];
    Sm[tc][ts] = sm; Sq[tc][ts] = sq;
    __syncthreads();
    if (t < 32) {
        float m = 0.f, q = 0.f;
#pragma unroll
        for (int j = 0; j < 8; ++j) { m += Sm[j][t]; q += Sq[j][t]; }
        float mu = m * (1.0f / EMBED);
        float var = q * (1.0f / EMBED) - mu * mu;
        muA[b * S_LEN + s0 + t] = mu;
        rsA[b * S_LEN + s0 + t] = rsqrtf(var + 1e-5f);
    }
}

// ---------------------------------------------------------------------------
// LN transpose+normalize: x[b,c,s] f32 -> xn[b,s,c] bf16 (32x32 LDS tile)
// ---------------------------------------------------------------------------
__global__ __launch_bounds__(256) void ln_tr_kernel(const float* __restrict__ x,
                                                    const float* __restrict__ muA,
                                                    const float* __restrict__ rsA,
                                                    const float* __restrict__ gamma,
                                                    const float* __restrict__ beta,
                                                    bf16_t* __restrict__ xn) {
    __shared__ float T[32][33];
    int tx = threadIdx.x & 31, ty = threadIdx.x >> 5;
    int b = blockIdx.z, c0 = blockIdx.y * 32, s0 = blockIdx.x * 32;
#pragma unroll
    for (int i = 0; i < 4; ++i) {
        int cr = ty + i * 8;
        T[cr][tx] = x[((size_t)b * EMBED + c0 + cr) * S_LEN + s0 + tx];
    }
    __syncthreads();
    float g = gamma[c0 + tx], be = beta[c0 + tx];
#pragma unroll
    for (int i = 0; i < 4; ++i) {
        int sr = ty + i * 8;
        float mu = muA[b * S_LEN + s0 + sr];
        float rs = rsA[b * S_LEN + s0 + sr];
        xn[((size_t)b * S_LEN + s0 + sr) * EMBED + c0 + tx] =
            f2bf((T[tx][sr] - mu) * rs * g + be);
    }
}

// ---------------------------------------------------------------------------
// Act-stationary GEMM  Y[m, col] = sum_k X[m,k]*W[col,k] + bias[col]
// (QK projection: W = packed [1024][512], bias split b0/b1 at col 512)
// k-chunked double-buffered LDS staging of W; X streamed w/ chunk prefetch.
// ---------------------------------------------------------------------------
__global__ __launch_bounds__(256) void gemm_kernel(const bf16_t* __restrict__ X,
                                                   const bf16_t* __restrict__ W,
                                                   const float* __restrict__ b0,
                                                   const float* __restrict__ b1,
                                                   bf16_t* __restrict__ Y, int ldY) {
    __shared__ __align__(16) bf16_t Wl[2][64 * 72];
    int t = threadIdx.x;
    int col0 = blockIdx.y * 64, row0 = blockIdx.x * 128;
    int scol = t >> 2, sseg = (t & 3) * 16;
    const bf16_t* wsrc = W + (size_t)(col0 + scol) * EMBED + sseg;
    {   // preload chunk 0
        bf16x8 r0 = *(const bf16x8*)(wsrc);
        bf16x8 r1 = *(const bf16x8*)(wsrc + 8);
        bf16_t* d = &Wl[0][scol * 72 + sseg];
        *(bf16x8*)d = r0; *(bf16x8*)(d + 8) = r1;
    }
    int lane = t & 63, w = t >> 6, g = lane >> 4, n16 = lane & 15;
    int rw0 = row0 + w * 32;
    const bf16_t* xr0 = X + (size_t)(rw0 + n16) * EMBED + g * 8;
    const bf16_t* xr1 = xr0 + (size_t)16 * EMBED;
    bf16x8 a00 = *(const bf16x8*)(xr0);
    bf16x8 a01 = *(const bf16x8*)(xr0 + 32);
    bf16x8 a10 = *(const bf16x8*)(xr1);
    bf16x8 a11 = *(const bf16x8*)(xr1 + 32);
    __syncthreads();
    floatx4 acc[2][4] = {};
#pragma unroll
    for (int kc = 0; kc < 8; ++kc) {
        bf16x8 p0, p1, na00, na01, na10, na11;
        if (kc < 7) {
            int ko = (kc + 1) * 64;
            p0 = *(const bf16x8*)(wsrc + ko);
            p1 = *(const bf16x8*)(wsrc + ko + 8);
            na00 = *(const bf16x8*)(xr0 + ko);
            na01 = *(const bf16x8*)(xr0 + ko + 32);
            na10 = *(const bf16x8*)(xr1 + ko);
            na11 = *(const bf16x8*)(xr1 + ko + 32);
        }
        const bf16_t* wl = &Wl[kc & 1][0];
#pragma unroll
        for (int kk = 0; kk < 2; ++kk) {
            bf16x8 s0 = (kk == 0) ? a00 : a01;
            bf16x8 s1 = (kk == 0) ? a10 : a11;
#pragma unroll
            for (int nt = 0; nt < 4; ++nt) {
                bf16x8 bfr = *(const bf16x8*)(&wl[(nt * 16 + n16) * 72 + kk * 32 + g * 8]);
                acc[0][nt] = MFMA16(s0, bfr, acc[0][nt]);
                acc[1][nt] = MFMA16(s1, bfr, acc[1][nt]);
            }
        }
        if (kc < 7) {
            bf16_t* d = &Wl[(kc + 1) & 1][scol * 72 + sseg];
            *(bf16x8*)d = p0; *(bf16x8*)(d + 8) = p1;
            a00 = na00; a01 = na01; a10 = na10; a11 = na11;
        }
        __syncthreads();
    }
#pragma unroll
    for (int ar = 0; ar < 2; ++ar)
#pragma unroll
        for (int nt = 0; nt < 4; ++nt) {
            int col = col0 + nt * 16 + n16;
            float bv = (col < 512) ? b0[col] : b1[col - 512];
#pragma unroll
            for (int r = 0; r < 4; ++r) {
                int row = rw0 + ar * 16 + g * 4 + r;
                Y[(size_t)row * ldY + col] = f2bf(acc[ar][nt][r] + bv);
            }
        }
}

// ---------------------------------------------------------------------------
// Weight-stationary GEMM, V-projection transposed output (padded row LDV):
// vt[b][m][n] = sum_k Wv[m][k] * xn[b][n][k] + bv[m]
// ---------------------------------------------------------------------------
__global__ __launch_bounds__(256) void wsgemm_vt_kernel(const bf16_t* __restrict__ Wb,
                                                        const bf16_t* __restrict__ act,
                                                        const float* __restrict__ bias,
                                                        bf16_t* __restrict__ vtb) {
    __shared__ __align__(16) bf16_t Al[2][64 * 72];
    int b = blockIdx.z, n0 = blockIdx.x * 64, m0 = blockIdx.y * 128;
    int t = threadIdx.x;
    int srow = t >> 2, sseg = (t & 3) * 16;
    const bf16_t* asrc = act + ((size_t)b * S_LEN + n0 + srow) * EMBED + sseg;
    {
        bf16x8 r0 = *(const bf16x8*)(asrc);
        bf16x8 r1 = *(const bf16x8*)(asrc + 8);
        bf16_t* d = &Al[0][srow * 72 + sseg];
        *(bf16x8*)d = r0; *(bf16x8*)(d + 8) = r1;
    }
    int lane = t & 63, w = t >> 6, g = lane >> 4, n16 = lane & 15;
    int mw = m0 + w * 32;
    const bf16_t* wr0 = Wb + (size_t)(mw + n16) * EMBED + g * 8;
    const bf16_t* wr1 = wr0 + (size_t)16 * EMBED;
    bf16x8 a00 = *(const bf16x8*)(wr0);
    bf16x8 a01 = *(const bf16x8*)(wr0 + 32);
    bf16x8 a10 = *(const bf16x8*)(wr1);
    bf16x8 a11 = *(const bf16x8*)(wr1 + 32);
    __syncthreads();
    floatx4 acc[2][4] = {};
#pragma unroll
    for (int kc = 0; kc < 8; ++kc) {
        bf16x8 p0, p1, na00, na01, na10, na11;
        if (kc < 7) {
            int ko = (kc + 1) * 64;
            p0 = *(const bf16x8*)(asrc + ko);
            p1 = *(const bf16x8*)(asrc + ko + 8);
            na00 = *(const bf16x8*)(wr0 + ko);
            na01 = *(const bf16x8*)(wr0 + ko + 32);
            na10 = *(const bf16x8*)(wr1 + ko);
            na11 = *(const bf16x8*)(wr1 + ko + 32);
        }
        const bf16_t* al = &Al[kc & 1][0];
#pragma unroll
        for (int kk = 0; kk < 2; ++kk) {
            bf16x8 s0 = (kk == 0) ? a00 : a01;
            bf16x8 s1 = (kk == 0) ? a10 : a11;
#pragma unroll
            for (int nt = 0; nt < 4; ++nt) {
                bf16x8 bfr = *(const bf16x8*)(&al[(nt * 16 + n16) * 72 + kk * 32 + g * 8]);
                acc[0][nt] = MFMA16(s0, bfr, acc[0][nt]);
                acc[1][nt] = MFMA16(s1, bfr, acc[1][nt]);
            }
        }
        if (kc < 7) {
            bf16_t* d = &Al[(kc + 1) & 1][srow * 72 + sseg];
            *(bf16x8*)d = p0; *(bf16x8*)(d + 8) = p1;
            a00 = na00; a01 = na01; a10 = na10; a11 = na11;
        }
        __syncthreads();
    }
#pragma unroll
    for (int ar = 0; ar < 2; ++ar)
#pragma unroll
        for (int r = 0; r < 4; ++r) {
            int row = mw + ar * 16 + g * 4 + r;
            float bv = bias[row];
#pragma unroll
            for (int nt = 0; nt < 4; ++nt) {
                int col = n0 + nt * 16 + n16;
                vtb[((size_t)b * EMBED + row) * LDV + col] = f2bf(acc[ar][nt][r] + bv);
            }
        }
}

// ---------------------------------------------------------------------------
// Weight-stationary GEMM, O-projection + bias + residual, NCHW f32 output
// ---------------------------------------------------------------------------
__global__ __launch_bounds__(256) void wsgemm_out_kernel(const bf16_t* __restrict__ Wb,
                                                         const bf16_t* __restrict__ act,
                                                         const float* __restrict__ bias,
                                                         const float* __restrict__ xres,
                                                         float* __restrict__ out) {
    __shared__ __align__(16) bf16_t Al[2][64 * 72];
    int b = blockIdx.z, n0 = blockIdx.x * 64, m0 = blockIdx.y * 128;
    int t = threadIdx.x;
    int srow = t >> 2, sseg = (t & 3) * 16;
    const bf16_t* asrc = act + ((size_t)b * S_LEN + n0 + srow) * EMBED + sseg;
    {
        bf16x8 r0 = *(const bf16x8*)(asrc);
        bf16x8 r1 = *(const bf16x8*)(asrc + 8);
        bf16_t* d = &Al[0][srow * 72 + sseg];
        *(bf16x8*)d = r0; *(bf16x8*)(d + 8) = r1;
    }
    int lane = t & 63, w = t >> 6, g = lane >> 4, n16 = lane & 15;
    int mw = m0 + w * 32;
    const bf16_t* wr0 = Wb + (size_t)(mw + n16) * EMBED + g * 8;
    const bf16_t* wr1 = wr0 + (size_t)16 * EMBED;
    bf16x8 a00 = *(const bf16x8*)(wr0);
    bf16x8 a01 = *(const bf16x8*)(wr0 + 32);
    bf16x8 a10 = *(const bf16x8*)(wr1);
    bf16x8 a11 = *(const bf16x8*)(wr1 + 32);
    __syncthreads();
    floatx4 acc[2][4] = {};
#pragma unroll
    for (int kc = 0; kc < 8; ++kc) {
        bf16x8 p0, p1, na00, na01, na10, na11;
        if (kc < 7) {
            int ko = (kc + 1) * 64;
            p0 = *(const bf16x8*)(asrc + ko);
            p1 = *(const bf16x8*)(asrc + ko + 8);
            na00 = *(const bf16x8*)(wr0 + ko);
            na01 = *(const bf16x8*)(wr0 + ko + 32);
            na10 = *(const bf16x8*)(wr1 + ko);
            na11 = *(const bf16x8*)(wr1 + ko + 32);
        }
        const bf16_t* al = &Al[kc & 1][0];
#pragma unroll
        for (int kk = 0; kk < 2; ++kk) {
            bf16x8 s0 = (kk == 0) ? a00 : a01;
            bf16x8 s1 = (kk == 0) ? a10 : a11;
#pragma unroll
            for (int nt = 0; nt < 4; ++nt) {
                bf16x8 bfr = *(const bf16x8*)(&al[(nt * 16 + n16) * 72 + kk * 32 + g * 8]);
                acc[0][nt] = MFMA16(s0, bfr, acc[0][nt]);
                acc[1][nt] = MFMA16(s1, bfr, acc[1][nt]);
            }
        }
        if (kc < 7) {
            bf16_t* d = &Al[(kc + 1) & 1][srow * 72 + sseg];
            *(bf16x8*)d = p0; *(bf16x8*)(d + 8) = p1;
            a00 = na00; a01 = na01; a10 = na10; a11 = na11;
        }
        __syncthreads();
    }
#pragma unroll
    for (int ar = 0; ar < 2; ++ar)
#pragma unroll
        for (int r = 0; r < 4; ++r) {
            int row = mw + ar * 16 + g * 4 + r;
            float bv = bias[row];
#pragma unroll
            for (int nt = 0; nt < 4; ++nt) {
                int col = n0 + nt * 16 + n16;
                size_t oi = ((size_t)b * EMBED + row) * S_LEN + col;
                out[oi] = acc[ar][nt][r] + bv + xres[oi];
            }
        }
}

// ---------------------------------------------------------------------------
// Flash attention, LDS-staged K/V^T tiles (coalesced, stride-72 rows,
// double-buffered, 1 barrier/iter), fixed-offset softmax, P via per-wave LDS.
// grid: bid&63=(b,h) [XCD L2 locality], bid>>6=qt (q-tile of 128).
// 4 waves; each wave owns 32 q (two 16-q halves sharing K/V fragments).
// ---------------------------------------------------------------------------
__global__ __launch_bounds__(256) void attn_kernel(const bf16_t* __restrict__ qk,
                                                   const bf16_t* __restrict__ vt,
                                                   bf16_t* __restrict__ o) {
    __shared__ __align__(16) bf16_t Kt[2][64 * 72];
    __shared__ __align__(16) bf16_t Vl2[2][64 * 72];
    __shared__ __align__(16) unsigned int Pl[4][16 * 36];
    int bid = blockIdx.x;
    int bh = bid & 63, qt = bid >> 6;           // qt 0..7
    int b = bh >> 3, h = bh & 7;
    int t = threadIdx.x, w = t >> 6, lane = t & 63, g = lane >> 4, n16 = lane & 15;
    size_t baseQK = (size_t)b * S_LEN * LDK;
    size_t baseV  = ((size_t)b * EMBED + h * HD) * LDV;
    int qA = qt * 128 + w * 32 + n16;

    // Q fragments for both 16-q halves, pre-scaled by 1/sqrt(64)
    const bf16_t* qpA = qk + baseQK + (size_t)qA * LDK + h * HD + g * 8;
    const bf16_t* qpB = qpA + (size_t)16 * LDK;
    bf16x8 qa0 = *(const bf16x8*)(qpA);
    bf16x8 qa1 = *(const bf16x8*)(qpA + 32);
    bf16x8 qb0 = *(const bf16x8*)(qpB);
    bf16x8 qb1 = *(const bf16x8*)(qpB + 32);
#pragma unroll
    for (int j = 0; j < 8; ++j) {
        qa0[j] = f2bf(bf2f(qa0[j]) * 0.125f);
        qa1[j] = f2bf(bf2f(qa1[j]) * 0.125f);
        qb0[j] = f2bf(bf2f(qb0[j]) * 0.125f);
        qb1[j] = f2bf(bf2f(qb1[j]) * 0.125f);
    }
    const bf16_t* kbase = qk + baseQK + 512 + h * HD;
    const bf16_t* vbase = vt + baseV;

    // cooperative staging: thread t -> row t>>2 (0..63), 16 elems at (t&3)*16
    int srow = t >> 2, scol = (t & 3) * 16;
    const bf16_t* ksrc = kbase + (size_t)srow * LDK + scol;
    const bf16_t* vsrc = vbase + (size_t)srow * LDV + scol;
    {   // preload tile 0
        bf16x8 k0 = *(const bf16x8*)(ksrc);
        bf16x8 k1 = *(const bf16x8*)(ksrc + 8);
        bf16x8 v0 = *(const bf16x8*)(vsrc);
        bf16x8 v1 = *(const bf16x8*)(vsrc + 8);
        bf16_t* kd = &Kt[0][srow * 72 + scol];
        bf16_t* vd = &Vl2[0][srow * 72 + scol];
        *(bf16x8*)kd = k0; *(bf16x8*)(kd + 8) = k1;
        *(bf16x8*)vd = v0; *(bf16x8*)(vd + 8) = v1;
    }

    float lsA[4] = {}, lsB[4] = {};
    floatx4 oaccA[4] = {}, oaccB[4] = {};
    unsigned int* PLw = &Pl[w][0];

    for (int it = 0; it < 16; ++it) {
        int cur = it & 1, nxt = cur ^ 1;
        __syncthreads();
        // prefetch next tile (global, coalesced) into regs
        bf16x8 pk0, pk1, pv0, pv1;
        if (it < 15) {
            const bf16_t* kp = ksrc + (size_t)(it + 1) * 64 * LDK;
            pk0 = *(const bf16x8*)(kp);
            pk1 = *(const bf16x8*)(kp + 8);
            const bf16_t* vp = vsrc + (it + 1) * 64;
            pv0 = *(const bf16x8*)(vp);
            pv1 = *(const bf16x8*)(vp + 8);
        }
        const bf16_t* Kl = &Kt[cur][0];
        const bf16_t* Vl = &Vl2[cur][0];
        // ---- S^T = K Q^T - 12 for both q-halves (K frags shared) ----
        floatx4 sA[4], sB[4];
#pragma unroll
        for (int kb = 0; kb < 4; ++kb) {
            bf16x8 k0 = *(const bf16x8*)(&Kl[(kb * 16 + n16) * 72 + g * 8]);
            bf16x8 k1 = *(const bf16x8*)(&Kl[(kb * 16 + n16) * 72 + 32 + g * 8]);
            sA[kb] = floatx4{-12.f, -12.f, -12.f, -12.f};
            sA[kb] = MFMA16(k0, qa0, sA[kb]);
            sA[kb] = MFMA16(k1, qa1, sA[kb]);
            sB[kb] = floatx4{-12.f, -12.f, -12.f, -12.f};
            sB[kb] = MFMA16(k0, qb0, sB[kb]);
            sB[kb] = MFMA16(k1, qb1, sB[kb]);
        }
        // ---- stage next tile to LDS[nxt] ----
        if (it < 15) {
            bf16_t* kd = &Kt[nxt][srow * 72 + scol];
            bf16_t* vd = &Vl2[nxt][srow * 72 + scol];
            *(bf16x8*)kd = pk0; *(bf16x8*)(kd + 8) = pk1;
            *(bf16x8*)vd = pv0; *(bf16x8*)(vd + 8) = pv1;
        }
        // ---- p = exp(s); per-lane l partials ----
#pragma unroll
        for (int kb = 0; kb < 4; ++kb)
#pragma unroll
            for (int r = 0; r < 4; ++r) {
                float eA = __expf(fminf(sA[kb][r], 40.f));
                sA[kb][r] = eA; lsA[kb] += eA;
                float eB = __expf(fminf(sB[kb][r], 40.f));
                sB[kb][r] = eB; lsB[kb] += eB;
            }
        // ---- P^T half A -> per-wave LDS -> B-frags (in-order DS pipe) ----
#pragma unroll
        for (int kb = 0; kb < 4; ++kb) {
            uint2 pr;
            pr.x = pack2(sA[kb][0], sA[kb][1]);
            pr.y = pack2(sA[kb][2], sA[kb][3]);
            *(uint2*)&PLw[n16 * 36 + kb * 8 + g * 2] = pr;
        }
        uint4 uA0 = *(const uint4*)&PLw[n16 * 36 + g * 4];
        uint4 uA1 = *(const uint4*)&PLw[n16 * 36 + 16 + g * 4];
        bf16x8 pfA0 = __builtin_bit_cast(bf16x8, uA0);
        bf16x8 pfA1 = __builtin_bit_cast(bf16x8, uA1);
        // ---- half B reuses the same region (program-order DS) ----
#pragma unroll
        for (int kb = 0; kb < 4; ++kb) {
            uint2 pr;
            pr.x = pack2(sB[kb][0], sB[kb][1]);
            pr.y = pack2(sB[kb][2], sB[kb][3]);
            *(uint2*)&PLw[n16 * 36 + kb * 8 + g * 2] = pr;
        }
        uint4 uB0 = *(const uint4*)&PLw[n16 * 36 + g * 4];
        uint4 uB1 = *(const uint4*)&PLw[n16 * 36 + 16 + g * 4];
        bf16x8 pfB0 = __builtin_bit_cast(bf16x8, uB0);
        bf16x8 pfB1 = __builtin_bit_cast(bf16x8, uB1);
        // ---- O^T += V^T P^T (V frags shared across halves) ----
#pragma unroll
        for (int dt = 0; dt < 4; ++dt) {
            bf16x8 v0 = *(const bf16x8*)(&Vl[(dt * 16 + n16) * 72 + g * 8]);
            bf16x8 v1 = *(const bf16x8*)(&Vl[(dt * 16 + n16) * 72 + 32 + g * 8]);
            oaccA[dt] = MFMA16(v0, pfA0, oaccA[dt]);
            oaccA[dt] = MFMA16(v1, pfA1, oaccA[dt]);
            oaccB[dt] = MFMA16(v0, pfB0, oaccB[dt]);
            oaccB[dt] = MFMA16(v1, pfB1, oaccB[dt]);
        }
    }
    // ---- l reductions (once) + epilogue for both halves ----
    float lA = (lsA[0] + lsA[1]) + (lsA[2] + lsA[3]);
    lA += __shfl_xor(lA, 16);
    lA += __shfl_xor(lA, 32);
    float lB = (lsB[0] + lsB[1]) + (lsB[2] + lsB[3]);
    lB += __shfl_xor(lB, 16);
    lB += __shfl_xor(lB, 32);
    float rlA = 1.0f / lA, rlB = 1.0f / lB;
    size_t orowA = ((size_t)b * S_LEN + qA) * EMBED + h * HD;
    size_t orowB = orowA + (size_t)16 * EMBED;
#pragma unroll
    for (int dt = 0; dt < 4; ++dt) {
        uint2 prA, prB;
        prA.x = pack2(oaccA[dt][0] * rlA, oaccA[dt][1] * rlA);
        prA.y = pack2(oaccA[dt][2] * rlA, oaccA[dt][3] * rlA);
        *(uint2*)(o + orowA + dt * 16 + g * 4) = prA;
        prB.x = pack2(oaccB[dt][0] * rlB, oaccB[dt][1] * rlB);
        prB.y = pack2(oaccB[dt][2] * rlB, oaccB[dt][3] * rlB);
        *(uint2*)(o + orowB + dt * 16 + g * 4) = prB;
    }
}

extern "C" void kernel_launch(void* const* d_in, const int* in_sizes, int n_in,
                              void* d_out, int out_size, void* d_ws, size_t ws_size,
                              hipStream_t stream) {
    const float* x     = (const float*)d_in[0];
    const float* Wq    = (const float*)d_in[1];
    const float* bq    = (const float*)d_in[2];
    const float* Wk    = (const float*)d_in[3];
    const float* bk    = (const float*)d_in[4];
    const float* Wv    = (const float*)d_in[5];
    const float* bv    = (const float*)d_in[6];
    const float* Wo    = (const float*)d_in[7];
    const float* bo    = (const float*)d_in[8];
    const float* gamma = (const float*)d_in[9];
    const float* beta  = (const float*)d_in[10];
    float* out = (float*)d_out;

    char* ws = (char*)d_ws;                        // ~27.9 MB used
    bf16_t* xn   = (bf16_t*)ws;                    // [0,8M); reused as attn-out
    bf16_t* qkb  = (bf16_t*)(ws + 8388608);        // packed QK [8192][1056] (17.3 MB)
    bf16_t* wqk  = (bf16_t*)(ws + 25690112);       // 1 MB packed [1024][512]
    bf16_t* wv   = (bf16_t*)(ws + 26738688);       // 512 KB
    bf16_t* wo   = (bf16_t*)(ws + 27262976);       // 512 KB
    float*  muA  = (float*)(ws + 27787264);        // 32 KB
    float*  rsA  = (float*)(ws + 27820032);        // 32 KB
    bf16_t* ab   = xn;

    // vt lives in d_out (8.9 MB used of 16.8): dead before wsgemm_out writes out
    bf16_t* vtb = (bf16_t*)d_out;

    cvt4_kernel<<<dim3(128, 4), 256, 0, stream>>>(Wq, Wk, Wv, Wo,
                                                  wqk, wqk + 262144, wv, wo);
    ln_stats_kernel<<<dim3(256), 256, 0, stream>>>(x, muA, rsA);
    ln_tr_kernel<<<dim3(32, 16, 8), 256, 0, stream>>>(x, muA, rsA, gamma, beta, xn);
    gemm_kernel<<<dim3(64, 16), 256, 0, stream>>>(xn, wqk, bq, bk, qkb, LDK);
    wsgemm_vt_kernel<<<dim3(16, 4, 8), 256, 0, stream>>>(wv, xn, bv, vtb);
    attn_kernel<<<dim3(512), 256, 0, stream>>>(qkb, vtb, ab);
    wsgemm_out_kernel<<<dim3(16, 4, 8), 256, 0, stream>>>(wo, ab, bo, x, out);
}